// Round 2
// baseline (2228.474 us; speedup 1.0000x reference)
//
#include <hip/hip_runtime.h>
#include <math.h>

// Problem constants (setup_inputs is fixed)
#define BB   4
#define HH   128
#define WW2  128
#define NN   (HH*WW2)     // 16384
#define CC   256
#define NH   8
#define HID  768
#define EPSF 1e-6f
#define SCALE 0.17677669529663687f   // 32^-0.5

// ---- bf16 helpers (raw ushort storage) ----
__device__ __forceinline__ float bf2f(ushort h) {
    union { unsigned u; float f; } x; x.u = ((unsigned)h) << 16; return x.f;
}
__device__ __forceinline__ ushort f2bf(float f) {
    union { float f; unsigned u; } x; x.f = f;
    unsigned r = (x.u + 0x7FFFu + ((x.u >> 16) & 1u)) >> 16;
    return (ushort)r;
}

// ---------------- LN row stats: mean & rstd per row (C=256) ----------------
// one wave per row, 4 rows per block
__global__ __launch_bounds__(256) void ln_stats(const float* __restrict__ in,
                                                float* __restrict__ mean,
                                                float* __restrict__ rstd) {
    int row = blockIdx.x*4 + (threadIdx.x >> 6);
    int lane = threadIdx.x & 63;
    float4 v = *(const float4*)&in[(size_t)row*CC + lane*4];
    float s  = v.x + v.y + v.z + v.w;
    float s2 = v.x*v.x + v.y*v.y + v.z*v.z + v.w*v.w;
    #pragma unroll
    for (int off = 32; off >= 1; off >>= 1) {
        s  += __shfl_down(s, off);
        s2 += __shfl_down(s2, off);
    }
    if (lane == 0) {
        float m = s * (1.0f/CC);
        float var = s2 * (1.0f/CC) - m*m;
        mean[row] = m;
        rstd[row] = rsqrtf(var + EPSF);
    }
}

// ---------------- tiled GEMM: C[M,N] = op(A)[M,K] @ B[K,N] + bias (+resid) ----------------
// 64x64 tile, BK=16, 256 threads, 4x4 per thread.
// TA: float (optionally LN-fused) or ushort (bf16). TC: float (with resid) or ushort (bf16).
template<int NDIM, int KDIM, typename TA, typename TC, bool LN>
__global__ __launch_bounds__(256) void gemm_kernel(const TA* __restrict__ A,
                                                   const float* __restrict__ Bm,
                                                   const float* __restrict__ bias,
                                                   const float* __restrict__ resid,
                                                   TC* __restrict__ Cm,
                                                   const float* __restrict__ mean,
                                                   const float* __restrict__ rstd,
                                                   const float* __restrict__ lng,
                                                   const float* __restrict__ lnb) {
    __shared__ float As[64][17];
    __shared__ float Bs[16][64];
    int tid = threadIdx.x;
    int tx = tid & 15, ty = tid >> 4;
    size_t mBase = (size_t)blockIdx.y * 64;
    int nBase = blockIdx.x * 64;
    float acc[4][4] = {};
    int aRow = tid >> 2;          // 0..63
    int aK4  = (tid & 3) * 4;     // 0,4,8,12
    int bN4  = (tid & 15) * 4;    // 0..60
    int bK   = tid >> 4;          // 0..15

    float m_r = 0.f, r_r = 0.f;
    if (LN) { m_r = mean[mBase + aRow]; r_r = rstd[mBase + aRow]; }

    for (int k0 = 0; k0 < KDIM; k0 += 16) {
        if constexpr (sizeof(TA) == 2) {
            ushort4 uv = *(const ushort4*)&A[(mBase + aRow)*(size_t)KDIM + k0 + aK4];
            As[aRow][aK4+0] = bf2f(uv.x); As[aRow][aK4+1] = bf2f(uv.y);
            As[aRow][aK4+2] = bf2f(uv.z); As[aRow][aK4+3] = bf2f(uv.w);
        } else if (LN) {
            float4 xv = *(const float4*)&((const float*)A)[(mBase + aRow)*(size_t)KDIM + k0 + aK4];
            float4 gv = *(const float4*)&lng[k0 + aK4];
            float4 bv = *(const float4*)&lnb[k0 + aK4];
            As[aRow][aK4+0] = (xv.x - m_r)*r_r*gv.x + bv.x;
            As[aRow][aK4+1] = (xv.y - m_r)*r_r*gv.y + bv.y;
            As[aRow][aK4+2] = (xv.z - m_r)*r_r*gv.z + bv.z;
            As[aRow][aK4+3] = (xv.w - m_r)*r_r*gv.w + bv.w;
        } else {
            float4 av = *(const float4*)&((const float*)A)[(mBase + aRow)*(size_t)KDIM + k0 + aK4];
            As[aRow][aK4+0]=av.x; As[aRow][aK4+1]=av.y; As[aRow][aK4+2]=av.z; As[aRow][aK4+3]=av.w;
        }
        float4 bv = *(const float4*)&Bm[(size_t)(k0 + bK)*NDIM + nBase + bN4];
        *(float4*)&Bs[bK][bN4] = bv;
        __syncthreads();
        #pragma unroll
        for (int k = 0; k < 16; ++k) {
            float ar[4], br[4];
            #pragma unroll
            for (int i = 0; i < 4; ++i) ar[i] = As[ty*4+i][k];
            #pragma unroll
            for (int j = 0; j < 4; ++j) br[j] = Bs[k][tx*4+j];
            #pragma unroll
            for (int i = 0; i < 4; ++i)
                #pragma unroll
                for (int j = 0; j < 4; ++j) acc[i][j] += ar[i]*br[j];
        }
        __syncthreads();
    }
    #pragma unroll
    for (int i = 0; i < 4; ++i) {
        if constexpr (sizeof(TC) == 2) {
            size_t idx = (mBase + ty*4+i)*(size_t)NDIM + nBase + tx*4;
            ushort4 pk;
            pk.x = f2bf(acc[i][0] + bias[nBase + tx*4 + 0]);
            pk.y = f2bf(acc[i][1] + bias[nBase + tx*4 + 1]);
            pk.z = f2bf(acc[i][2] + bias[nBase + tx*4 + 2]);
            pk.w = f2bf(acc[i][3] + bias[nBase + tx*4 + 3]);
            *(ushort4*)&Cm[idx] = pk;
        } else {
            #pragma unroll
            for (int j = 0; j < 4; ++j) {
                size_t idx = (mBase + ty*4+i)*(size_t)NDIM + nBase + tx*4 + j;
                float r = acc[i][j] + bias[nBase + tx*4 + j];
                if (resid) r += resid[idx];
                ((float*)Cm)[idx] = r;
            }
        }
    }
}

// ------------- softmax over tokens: partial (m,s) per 256-token chunk per (b,h,kd) -------------
__global__ __launch_bounds__(256) void col_softmax_partial(const ushort* __restrict__ qkv,
                                                           float* __restrict__ pmax,
                                                           float* __restrict__ psum) {
    int blk = blockIdx.x;
    int chunk = blk & 63;
    int bh = blk >> 6;          // 0..31
    int b = bh >> 3, hh = bh & 7;
    int tid = threadIdx.x;
    int kd = tid & 31, nt = tid >> 5;   // 8-way token parallel
    int n0 = chunk * 256;
    const ushort* base = qkv + (size_t)b*NN*768 + 256 + hh*32 + kd;
    float m = -INFINITY, s = 0.f;
    for (int i = 0; i < 32; ++i) {
        int n = n0 + nt + i*8;
        float v = bf2f(base[(size_t)n*768]);
        float nm = fmaxf(m, v);
        s = s*expf(m-nm) + expf(v-nm);
        m = nm;
    }
    __shared__ float sm[256], ss[256];
    sm[tid] = m; ss[tid] = s;
    __syncthreads();
    if (nt == 0) {
        for (int j = 1; j < 8; ++j) {
            float m2 = sm[j*32+kd], s2 = ss[j*32+kd];
            float nm = fmaxf(m, m2);
            s = s*expf(m-nm) + s2*expf(m2-nm);
            m = nm;
        }
        int p = (bh*64 + chunk)*32 + kd;
        pmax[p] = m; psum[p] = s;
    }
}

__global__ void col_softmax_final(const float* __restrict__ pmax, const float* __restrict__ psum,
                                  float* __restrict__ colmax, float* __restrict__ colsum) {
    int bh = blockIdx.x;          // 32
    int kd = threadIdx.x;         // 32
    float m = -INFINITY, s = 0.f;
    for (int ch = 0; ch < 64; ++ch) {
        int p = (bh*64 + ch)*32 + kd;
        float m2 = pmax[p], s2 = psum[p];
        float nm = fmaxf(m, m2);
        s = s*expf(m-nm) + s2*expf(m2-nm);
        m = nm;
    }
    colmax[bh*32+kd] = m;
    colsum[bh*32+kd] = s;
}

__global__ void zero_kernel(float* __restrict__ p, int nElems) {
    int i = blockIdx.x*256 + threadIdx.x;
    if (i < nElems) p[i] = 0.f;
}

// ------------- kv_raw[bh,kd,vd] += sum_n exp(k-max)*v over a 1024-token chunk -------------
__global__ __launch_bounds__(256) void kv_partial(const ushort* __restrict__ qkv,
                                                  const float* __restrict__ colmax,
                                                  float* __restrict__ kv_raw) {
    int blk = blockIdx.x;
    int chunk = blk & 15;
    int bh = blk >> 4;
    int b = bh >> 3, hh = bh & 7;
    int tid = threadIdx.x;
    __shared__ float ke[32][33];
    __shared__ float vv[32][33];
    __shared__ float cmax[32];
    if (tid < 32) cmax[tid] = colmax[bh*32 + tid];
    int kd = tid >> 3;            // 0..31
    int v0 = (tid & 7) * 4;       // 0..28
    int t  = tid >> 5;            // 0..7
    int cc = tid & 31;
    float acc0=0.f, acc1=0.f, acc2=0.f, acc3=0.f;
    __syncthreads();
    for (int it = 0; it < 32; ++it) {
        int nb = chunk*1024 + it*32;
        #pragma unroll
        for (int r = 0; r < 4; ++r) {
            int tt = t + r*8;
            size_t rowoff = ((size_t)b*NN + nb + tt)*768;
            float kval = bf2f(qkv[rowoff + 256 + hh*32 + cc]);
            ke[tt][cc] = expf(kval - cmax[cc]);
            vv[tt][cc] = bf2f(qkv[rowoff + 512 + hh*32 + cc]);
        }
        __syncthreads();
        #pragma unroll
        for (int tt = 0; tt < 32; ++tt) {
            float kval = ke[tt][kd];
            acc0 += kval*vv[tt][v0+0];
            acc1 += kval*vv[tt][v0+1];
            acc2 += kval*vv[tt][v0+2];
            acc3 += kval*vv[tt][v0+3];
        }
        __syncthreads();
    }
    float* dst = kv_raw + ((size_t)bh*32 + kd)*32 + v0;
    atomicAdd(dst+0, acc0); atomicAdd(dst+1, acc1);
    atomicAdd(dst+2, acc2); atomicAdd(dst+3, acc3);
}

__global__ void kv_finalize(const float* __restrict__ kv_raw, const float* __restrict__ colsum,
                            float* __restrict__ kv) {
    int i = blockIdx.x*256 + threadIdx.x;     // 32768 total
    if (i >= 32768) return;
    int kd = (i >> 5) & 31;
    int bh = i >> 10;
    kv[i] = kv_raw[i] / colsum[bh*32 + kd];
}

// ------------- att = scale*(q@kv) + q * dwconv3x3(v), fused; output [B,N,C] fp32 -------------
__global__ __launch_bounds__(256) void attn_combine(const ushort* __restrict__ qkv,
                                                    const float* __restrict__ kv,
                                                    const float* __restrict__ w,
                                                    const float* __restrict__ wb,
                                                    float* __restrict__ att) {
    int bn = blockIdx.x;
    int b = bn >> 14;
    int n = bn & (NN-1);
    int hh = n >> 7, ww = n & 127;
    int c = threadIdx.x;
    int hd = c >> 5, vd = c & 31;
    __shared__ float qrow[256];
    qrow[c] = bf2f(qkv[(size_t)bn*768 + c]);
    __syncthreads();
    float conv = wb[c];
    const float* wc = w + c*9;
    #pragma unroll
    for (int dy = -1; dy <= 1; ++dy) {
        int y = hh + dy;
        if ((unsigned)y >= HH) continue;
        #pragma unroll
        for (int dx = -1; dx <= 1; ++dx) {
            int x = ww + dx;
            if ((unsigned)x >= WW2) continue;
            conv += wc[(dy+1)*3 + (dx+1)] * bf2f(qkv[((size_t)b*NN + y*WW2 + x)*768 + 512 + c]);
        }
    }
    const float* kvp = kv + ((size_t)(b*NH + hd))*1024 + vd;
    float f = 0.f;
    #pragma unroll
    for (int kd = 0; kd < 32; ++kd) f += qrow[hd*32+kd] * kvp[kd*32];
    att[(size_t)bn*CC + c] = SCALE*f + qrow[c]*conv;
}

// ------------- MLP depthwise 3x3 + bias + skip + exact GELU on one batch image -------------
__global__ __launch_bounds__(768) void dconv_gelu(const ushort* __restrict__ hdn_b,
                                                  const float* __restrict__ w,
                                                  const float* __restrict__ bias,
                                                  ushort* __restrict__ out) {
    int n = blockIdx.x;           // 0..16383 (batch-local)
    int hh = n >> 7, ww = n & 127;
    int c = threadIdx.x;          // 0..767
    float acc = bias[c];
    const float* wc = w + c*9;
    #pragma unroll
    for (int dy = -1; dy <= 1; ++dy) {
        int y = hh + dy;
        if ((unsigned)y >= HH) continue;
        #pragma unroll
        for (int dx = -1; dx <= 1; ++dx) {
            int x = ww + dx;
            if ((unsigned)x >= WW2) continue;
            acc += wc[(dy+1)*3 + (dx+1)] * bf2f(hdn_b[((size_t)y*WW2 + x)*HID + c]);
        }
    }
    float v = bf2f(hdn_b[(size_t)n*HID + c]) + acc;
    out[(size_t)n*HID + c] = f2bf(0.5f*v*(1.f + erff(v*0.70710678118654752f)));
}

extern "C" void kernel_launch(void* const* d_in, const int* in_sizes, int n_in,
                              void* d_out, int out_size, void* d_ws, size_t ws_size,
                              hipStream_t stream) {
    const float* x      = (const float*)d_in[0];
    const float* ln1_g  = (const float*)d_in[3];
    const float* ln1_b  = (const float*)d_in[4];
    const float* qkv_w  = (const float*)d_in[5];
    const float* qkv_b  = (const float*)d_in[6];
    const float* crpe_w = (const float*)d_in[7];
    const float* crpe_b = (const float*)d_in[8];
    const float* proj_w = (const float*)d_in[9];
    const float* proj_b = (const float*)d_in[10];
    const float* ln2_g  = (const float*)d_in[11];
    const float* ln2_b  = (const float*)d_in[12];
    const float* fc1_w  = (const float*)d_in[13];
    const float* fc1_b  = (const float*)d_in[14];
    const float* dconv_w= (const float*)d_in[15];
    const float* dconv_b= (const float*)d_in[16];
    const float* fc2_w  = (const float*)d_in[17];
    const float* fc2_b  = (const float*)d_in[18];
    float* out = (float*)d_out;
    float* ws  = (float*)d_ws;

    // Workspace arena — total ~48.7M float-slots ≈ 195 MB
    ushort* qkvH = (ushort*)ws;                    // 50,331,648 bf16 (qkv; later hdn)
    float* x2    = ws + 25165824;                  // 16,777,216 f32
    float* mean1 = x2 + 16777216;                  // 65,536
    float* rstd1 = mean1 + 65536;                  // 65,536
    float* mean2 = rstd1 + 65536;                  // 65,536
    float* rstd2 = mean2 + 65536;                  // 65,536
    float* pmax  = rstd2 + 65536;                  // 65,536
    float* psum  = pmax + 65536;                   // 65,536
    float* cmaxB = psum + 65536;                   // 1,024
    float* csumB = cmaxB + 1024;                   // 1,024
    float* kvraw = csumB + 1024;                   // 32,768
    float* kvB   = kvraw + 32768;                  // 32,768
    ushort* hdn2 = (ushort*)(kvB + 32768);         // 12,582,912 bf16 (per-batch dconv out)

    float* att = out;   // use d_out as fp32 scratch for the attention output
    const int ROWS = BB*NN;   // 65536

    // ---- attention branch ----
    ln_stats<<<ROWS/4, 256, 0, stream>>>(x, mean1, rstd1);
    gemm_kernel<768,256,float,ushort,true><<<dim3(12,1024), 256, 0, stream>>>(
        x, qkv_w, qkv_b, nullptr, qkvH, mean1, rstd1, ln1_g, ln1_b);
    col_softmax_partial<<<BB*NH*64, 256, 0, stream>>>(qkvH, pmax, psum);
    col_softmax_final<<<32, 32, 0, stream>>>(pmax, psum, cmaxB, csumB);
    zero_kernel<<<128, 256, 0, stream>>>(kvraw, 32768);
    kv_partial<<<BB*NH*16, 256, 0, stream>>>(qkvH, cmaxB, kvraw);
    kv_finalize<<<128, 256, 0, stream>>>(kvraw, csumB, kvB);
    attn_combine<<<ROWS, 256, 0, stream>>>(qkvH, kvB, crpe_w, crpe_b, att);
    gemm_kernel<256,256,float,float,false><<<dim3(4,1024), 256, 0, stream>>>(
        att, proj_w, proj_b, x, x2, nullptr, nullptr, nullptr, nullptr);

    // ---- conv-MLP branch ----
    ln_stats<<<ROWS/4, 256, 0, stream>>>(x2, mean2, rstd2);
    gemm_kernel<768,256,float,ushort,true><<<dim3(12,1024), 256, 0, stream>>>(
        x2, fc1_w, fc1_b, nullptr, qkvH, mean2, rstd2, ln2_g, ln2_b);
    for (int b = 0; b < BB; ++b) {
        const ushort* hdn_b = qkvH + (size_t)b*NN*HID;
        size_t roff = (size_t)b*NN;
        dconv_gelu<<<NN, 768, 0, stream>>>(hdn_b, dconv_w, dconv_b, hdn2);
        gemm_kernel<256,768,ushort,float,false><<<dim3(4,256), 256, 0, stream>>>(
            hdn2, fc2_w, fc2_b, x2 + roff*CC, out + roff*CC,
            nullptr, nullptr, nullptr, nullptr);
    }
}

// Round 3
// 1252.887 us; speedup vs baseline: 1.7787x; 1.7787x over previous
//
#include <hip/hip_runtime.h>
#include <math.h>

// Problem constants (setup_inputs is fixed)
#define BB   4
#define HH   128
#define WW2  128
#define NN   (HH*WW2)     // 16384
#define CC   256
#define NH   8
#define HID  768
#define EPSF 1e-6f
#define SCALE 0.17677669529663687f   // 32^-0.5

typedef __attribute__((ext_vector_type(8))) short s8v;   // 8 bf16 (4 VGPRs) MFMA A/B frag
typedef __attribute__((ext_vector_type(4))) float f4v;   // MFMA C/D frag

// ---- bf16 helpers (raw ushort storage) ----
__device__ __forceinline__ float bf2f(ushort h) {
    union { unsigned u; float f; } x; x.u = ((unsigned)h) << 16; return x.f;
}
__device__ __forceinline__ ushort f2bf(float f) {
    union { float f; unsigned u; } x; x.f = f;
    unsigned r = (x.u + 0x7FFFu + ((x.u >> 16) & 1u)) >> 16;
    return (ushort)r;
}

typedef __attribute__((address_space(1))) unsigned gu32;
typedef __attribute__((address_space(3))) unsigned lu32;
__device__ __forceinline__ void gl_lds16(const void* g, void* l) {
    // async global->LDS, 16B per lane; LDS dst = wave-uniform base + lane*16
    __builtin_amdgcn_global_load_lds((gu32*)g, (lu32*)l, 16, 0, 0);
}

// ---------------- LayerNorm -> bf16, one block (256 thr) per row ----------------
__global__ __launch_bounds__(256) void ln_bf16(const float* __restrict__ in,
                                               const float* __restrict__ g,
                                               const float* __restrict__ bta,
                                               ushort* __restrict__ out) {
    int row = blockIdx.x;
    int tid = threadIdx.x;
    float v = in[(size_t)row*CC + tid];
    float s = v;
    #pragma unroll
    for (int off = 32; off >= 1; off >>= 1) s += __shfl_down(s, off);
    __shared__ float red[4];
    int wid = tid >> 6, lane = tid & 63;
    if (lane == 0) red[wid] = s;
    __syncthreads();
    float mean = (red[0]+red[1]+red[2]+red[3]) * (1.0f/CC);
    __syncthreads();
    float dv = v - mean;
    float s2 = dv*dv;
    #pragma unroll
    for (int off = 32; off >= 1; off >>= 1) s2 += __shfl_down(s2, off);
    if (lane == 0) red[wid] = s2;
    __syncthreads();
    float var = (red[0]+red[1]+red[2]+red[3]) * (1.0f/CC);
    out[(size_t)row*CC + tid] = f2bf(dv * rsqrtf(var + EPSF) * g[tid] + bta[tid]);
}

// ---------------- weight transpose + bf16 cast: w[K][N] -> wt[N][K] ----------------
__global__ __launch_bounds__(256) void wtrans(const float* __restrict__ w,
                                              ushort* __restrict__ wt, int K, int N) {
    int i = blockIdx.x*256 + threadIdx.x;
    if (i >= K*N) return;
    int k = i / N, n = i - k*N;
    wt[(size_t)n*K + k] = f2bf(w[i]);
}

// ---------------- bf16 MFMA GEMM: C[M,N] = A[M,K] @ Bt[N,K]^T + bias (+resid) ----------------
// 128x128 tile, BK=32, 256 threads (4 waves, 2x2), each wave 4x4 frags of 16x16x32.
// OUTBF: write bf16 (no resid). else: fp32 out = acc + bias + resid (resid fp32, may alias out).
template<int KDIM, bool OUTBF>
__global__ __launch_bounds__(256) void mfma_gemm(const ushort* __restrict__ A,
                                                 const ushort* __restrict__ Bt,
                                                 const float* __restrict__ bias,
                                                 const float* __restrict__ resid,
                                                 void* __restrict__ Cout,
                                                 int NDIM) {
    __shared__ ushort lsA[128*32];   // [row][k] bf16, no pad (global_load_lds lane order)
    __shared__ ushort lsB[128*32];   // [n]  [k] bf16
    int tid  = threadIdx.x;
    int lane = tid & 63;
    int w    = tid >> 6;
    int wm   = w >> 1, wn = w & 1;
    size_t mBase = (size_t)blockIdx.y * 128;
    int    nBase = blockIdx.x * 128;
    int lrow = lane & 15, lq = lane >> 4;

    // staging addresses: wave w covers tile rows [w*32, w*32+32), 16 rows per inst
    const ushort* gA = A  + (mBase + w*32 + (lane>>2))*(size_t)KDIM + (lane&3)*8;
    const ushort* gB = Bt + ((size_t)(nBase + w*32 + (lane>>2)))*(size_t)KDIM + (lane&3)*8;
    ushort* lA = lsA + w*1024;
    ushort* lB = lsB + w*1024;

    f4v acc[4][4] = {};

    for (int k0 = 0; k0 < KDIM; k0 += 32) {
        gl_lds16(gA + k0,           lA);
        gl_lds16(gA + k0 + 16*KDIM, lA + 512);
        gl_lds16(gB + k0,           lB);
        gl_lds16(gB + k0 + 16*KDIM, lB + 512);
        __syncthreads();
        s8v af[4], bf[4];
        #pragma unroll
        for (int i = 0; i < 4; ++i)
            af[i] = *(const s8v*)&lsA[(wm*64 + i*16 + lrow)*32 + lq*8];
        #pragma unroll
        for (int j = 0; j < 4; ++j)
            bf[j] = *(const s8v*)&lsB[(wn*64 + j*16 + lrow)*32 + lq*8];
        #pragma unroll
        for (int i = 0; i < 4; ++i)
            #pragma unroll
            for (int j = 0; j < 4; ++j)
                acc[i][j] = __builtin_amdgcn_mfma_f32_16x16x32_bf16(af[i], bf[j], acc[i][j], 0, 0, 0);
        __syncthreads();
    }

    // epilogue: C/D layout col=lane&15, row=(lane>>4)*4+reg
    int colBase = nBase + wn*64;
    #pragma unroll
    for (int j = 0; j < 4; ++j) {
        int col = colBase + j*16 + lrow;
        float bs = bias[col];
        #pragma unroll
        for (int i = 0; i < 4; ++i) {
            #pragma unroll
            for (int r = 0; r < 4; ++r) {
                size_t row = mBase + wm*64 + i*16 + lq*4 + r;
                size_t idx = row*(size_t)NDIM + col;
                float v = acc[i][j][r] + bs;
                if constexpr (OUTBF) ((ushort*)Cout)[idx] = f2bf(v);
                else                 ((float*)Cout)[idx] = v + resid[idx];
            }
        }
    }
}

// ------------- softmax over tokens: partial (m,s) per 256-token chunk per (b,h,kd) -------------
__global__ __launch_bounds__(256) void col_softmax_partial(const ushort* __restrict__ qkv,
                                                           float* __restrict__ pmax,
                                                           float* __restrict__ psum) {
    int blk = blockIdx.x;
    int chunk = blk & 63;
    int bh = blk >> 6;          // 0..31
    int b = bh >> 3, hh = bh & 7;
    int tid = threadIdx.x;
    int kd = tid & 31, nt = tid >> 5;
    int n0 = chunk * 256;
    const ushort* base = qkv + (size_t)b*NN*768 + 256 + hh*32 + kd;
    float m = -INFINITY, s = 0.f;
    for (int i = 0; i < 32; ++i) {
        int n = n0 + nt + i*8;
        float v = bf2f(base[(size_t)n*768]);
        float nm = fmaxf(m, v);
        s = s*expf(m-nm) + expf(v-nm);
        m = nm;
    }
    __shared__ float sm[256], ss[256];
    sm[tid] = m; ss[tid] = s;
    __syncthreads();
    if (nt == 0) {
        for (int j = 1; j < 8; ++j) {
            float m2 = sm[j*32+kd], s2 = ss[j*32+kd];
            float nm = fmaxf(m, m2);
            s = s*expf(m-nm) + s2*expf(m2-nm);
            m = nm;
        }
        int p = (bh*64 + chunk)*32 + kd;
        pmax[p] = m; psum[p] = s;
    }
}

__global__ void col_softmax_final(const float* __restrict__ pmax, const float* __restrict__ psum,
                                  float* __restrict__ colmax, float* __restrict__ colsum) {
    int bh = blockIdx.x;          // 32
    int kd = threadIdx.x;         // 32
    float m = -INFINITY, s = 0.f;
    for (int ch = 0; ch < 64; ++ch) {
        int p = (bh*64 + ch)*32 + kd;
        float m2 = pmax[p], s2 = psum[p];
        float nm = fmaxf(m, m2);
        s = s*expf(m-nm) + s2*expf(m2-nm);
        m = nm;
    }
    colmax[bh*32+kd] = m;
    colsum[bh*32+kd] = s;
}

__global__ void zero_kernel(float* __restrict__ p, int nElems) {
    int i = blockIdx.x*256 + threadIdx.x;
    if (i < nElems) p[i] = 0.f;
}

// ------------- kv_raw[bh,kd,vd] += sum_n exp(k-max)*v over a 1024-token chunk -------------
__global__ __launch_bounds__(256) void kv_partial(const ushort* __restrict__ qkv,
                                                  const float* __restrict__ colmax,
                                                  float* __restrict__ kv_raw) {
    int blk = blockIdx.x;
    int chunk = blk & 15;
    int bh = blk >> 4;
    int b = bh >> 3, hh = bh & 7;
    int tid = threadIdx.x;
    __shared__ float ke[32][33];
    __shared__ float vv[32][33];
    __shared__ float cmax[32];
    if (tid < 32) cmax[tid] = colmax[bh*32 + tid];
    int kd = tid >> 3;
    int v0 = (tid & 7) * 4;
    int t  = tid >> 5;
    int cc = tid & 31;
    float acc0=0.f, acc1=0.f, acc2=0.f, acc3=0.f;
    __syncthreads();
    for (int it = 0; it < 32; ++it) {
        int nb = chunk*1024 + it*32;
        #pragma unroll
        for (int r = 0; r < 4; ++r) {
            int tt = t + r*8;
            size_t rowoff = ((size_t)b*NN + nb + tt)*768;
            float kval = bf2f(qkv[rowoff + 256 + hh*32 + cc]);
            ke[tt][cc] = expf(kval - cmax[cc]);
            vv[tt][cc] = bf2f(qkv[rowoff + 512 + hh*32 + cc]);
        }
        __syncthreads();
        #pragma unroll
        for (int tt = 0; tt < 32; ++tt) {
            float kval = ke[tt][kd];
            acc0 += kval*vv[tt][v0+0];
            acc1 += kval*vv[tt][v0+1];
            acc2 += kval*vv[tt][v0+2];
            acc3 += kval*vv[tt][v0+3];
        }
        __syncthreads();
    }
    float* dst = kv_raw + ((size_t)bh*32 + kd)*32 + v0;
    atomicAdd(dst+0, acc0); atomicAdd(dst+1, acc1);
    atomicAdd(dst+2, acc2); atomicAdd(dst+3, acc3);
}

__global__ void kv_finalize(const float* __restrict__ kv_raw, const float* __restrict__ colsum,
                            float* __restrict__ kv) {
    int i = blockIdx.x*256 + threadIdx.x;     // 32768 total
    if (i >= 32768) return;
    int kd = (i >> 5) & 31;
    int bh = i >> 10;
    kv[i] = kv_raw[i] / colsum[bh*32 + kd];
}

// ------------- att = scale*(q@kv) + q * dwconv3x3(v), fused; output [B,N,C] bf16 -------------
__global__ __launch_bounds__(256) void attn_combine(const ushort* __restrict__ qkv,
                                                    const float* __restrict__ kv,
                                                    const float* __restrict__ w,
                                                    const float* __restrict__ wb,
                                                    ushort* __restrict__ att) {
    int bn = blockIdx.x;
    int b = bn >> 14;
    int n = bn & (NN-1);
    int hh = n >> 7, ww = n & 127;
    int c = threadIdx.x;
    int hd = c >> 5, vd = c & 31;
    __shared__ float qrow[256];
    qrow[c] = bf2f(qkv[(size_t)bn*768 + c]);
    __syncthreads();
    float conv = wb[c];
    const float* wc = w + c*9;
    #pragma unroll
    for (int dy = -1; dy <= 1; ++dy) {
        int y = hh + dy;
        if ((unsigned)y >= HH) continue;
        #pragma unroll
        for (int dx = -1; dx <= 1; ++dx) {
            int x = ww + dx;
            if ((unsigned)x >= WW2) continue;
            conv += wc[(dy+1)*3 + (dx+1)] * bf2f(qkv[((size_t)b*NN + y*WW2 + x)*768 + 512 + c]);
        }
    }
    const float* kvp = kv + ((size_t)(b*NH + hd))*1024 + vd;
    float f = 0.f;
    #pragma unroll
    for (int kd = 0; kd < 32; ++kd) f += qrow[hd*32+kd] * kvp[kd*32];
    att[(size_t)bn*CC + c] = f2bf(SCALE*f + qrow[c]*conv);
}

// ------------- MLP depthwise 3x3 + bias + skip + exact GELU on one batch image -------------
__global__ __launch_bounds__(768) void dconv_gelu(const ushort* __restrict__ hdn_b,
                                                  const float* __restrict__ w,
                                                  const float* __restrict__ bias,
                                                  ushort* __restrict__ out) {
    int n = blockIdx.x;           // 0..16383 (batch-local)
    int hh = n >> 7, ww = n & 127;
    int c = threadIdx.x;          // 0..767
    float acc = bias[c];
    const float* wc = w + c*9;
    #pragma unroll
    for (int dy = -1; dy <= 1; ++dy) {
        int y = hh + dy;
        if ((unsigned)y >= HH) continue;
        #pragma unroll
        for (int dx = -1; dx <= 1; ++dx) {
            int x = ww + dx;
            if ((unsigned)x >= WW2) continue;
            acc += wc[(dy+1)*3 + (dx+1)] * bf2f(hdn_b[((size_t)y*WW2 + x)*HID + c]);
        }
    }
    float v = bf2f(hdn_b[(size_t)n*HID + c]) + acc;
    out[(size_t)n*HID + c] = f2bf(0.5f*v*(1.f + erff(v*0.70710678118654752f)));
}

extern "C" void kernel_launch(void* const* d_in, const int* in_sizes, int n_in,
                              void* d_out, int out_size, void* d_ws, size_t ws_size,
                              hipStream_t stream) {
    const float* x      = (const float*)d_in[0];
    const float* ln1_g  = (const float*)d_in[3];
    const float* ln1_b  = (const float*)d_in[4];
    const float* qkv_w  = (const float*)d_in[5];
    const float* qkv_b  = (const float*)d_in[6];
    const float* crpe_w = (const float*)d_in[7];
    const float* crpe_b = (const float*)d_in[8];
    const float* proj_w = (const float*)d_in[9];
    const float* proj_b = (const float*)d_in[10];
    const float* ln2_g  = (const float*)d_in[11];
    const float* ln2_b  = (const float*)d_in[12];
    const float* fc1_w  = (const float*)d_in[13];
    const float* fc1_b  = (const float*)d_in[14];
    const float* dconv_w= (const float*)d_in[15];
    const float* dconv_b= (const float*)d_in[16];
    const float* fc2_w  = (const float*)d_in[17];
    const float* fc2_b  = (const float*)d_in[18];
    float* outF = (float*)d_out;
    ushort* ws16 = (ushort*)d_ws;

    // Workspace arena (ushort units) — total ~161.5 MB
    ushort* qkvH  = ws16;                    // 50,331,648  (qkv; later hdn)
    ushort* hdn2  = qkvH + 50331648;         // 12,582,912  (per-batch dconv out)
    ushort* sbuf  = hdn2 + 12582912;         // 16,777,216  (lnout1 / att / lnout2, disjoint lifetimes)
    ushort* wqkvT = sbuf + 16777216;         // 196,608
    ushort* wprojT= wqkvT + 196608;          // 65,536
    ushort* wfc1T = wprojT + 65536;          // 196,608
    ushort* wfc2T = wfc1T + 196608;          // 196,608
    float*  pmax  = (float*)(wfc2T + 196608);
    float*  psum  = pmax + 65536;
    float*  cmaxB = psum + 65536;
    float*  csumB = cmaxB + 1024;
    float*  kvraw = csumB + 1024;
    float*  kvB   = kvraw + 32768;

    const int ROWS = BB*NN;   // 65536

    // ---- weight prep (order-independent) ----
    wtrans<<<768, 256, 0, stream>>>(qkv_w,  wqkvT, CC,  3*CC);
    wtrans<<<256, 256, 0, stream>>>(proj_w, wprojT, CC,  CC);
    wtrans<<<768, 256, 0, stream>>>(fc1_w,  wfc1T, CC,  HID);
    wtrans<<<768, 256, 0, stream>>>(fc2_w,  wfc2T, HID, CC);

    // ---- attention branch ----
    ln_bf16<<<ROWS, 256, 0, stream>>>(x, ln1_g, ln1_b, sbuf);
    mfma_gemm<256, true><<<dim3(6, 512), 256, 0, stream>>>(sbuf, wqkvT, qkv_b, nullptr, qkvH, 768);
    col_softmax_partial<<<BB*NH*64, 256, 0, stream>>>(qkvH, pmax, psum);
    col_softmax_final<<<32, 32, 0, stream>>>(pmax, psum, cmaxB, csumB);
    zero_kernel<<<128, 256, 0, stream>>>(kvraw, 32768);
    kv_partial<<<BB*NH*16, 256, 0, stream>>>(qkvH, cmaxB, kvraw);
    kv_finalize<<<128, 256, 0, stream>>>(kvraw, csumB, kvB);
    attn_combine<<<ROWS, 256, 0, stream>>>(qkvH, kvB, crpe_w, crpe_b, sbuf);
    // x2 = x + att @ proj_w  -> lives in d_out (fp32)
    mfma_gemm<256, false><<<dim3(2, 512), 256, 0, stream>>>(sbuf, wprojT, proj_b, x, outF, 256);

    // ---- conv-MLP branch ----
    ln_bf16<<<ROWS, 256, 0, stream>>>(outF, ln2_g, ln2_b, sbuf);
    mfma_gemm<256, true><<<dim3(6, 512), 256, 0, stream>>>(sbuf, wfc1T, fc1_b, nullptr, qkvH, 768);
    for (int b = 0; b < BB; ++b) {
        const ushort* hdn_b = qkvH + (size_t)b*NN*HID;
        float* xo = outF + (size_t)b*NN*CC;
        dconv_gelu<<<NN, 768, 0, stream>>>(hdn_b, dconv_w, dconv_b, hdn2);
        // out = x2 + hdn2 @ fc2_w, in-place on d_out (same-element read-then-write)
        mfma_gemm<768, false><<<dim3(2, 128), 256, 0, stream>>>(hdn2, wfc2T, fc2_b, xo, xo, 256);
    }
}

// Round 4
// 722.251 us; speedup vs baseline: 3.0855x; 1.7347x over previous
//
#include <hip/hip_runtime.h>
#include <math.h>

// Problem constants (setup_inputs is fixed)
#define BB   4
#define HH   128
#define WW2  128
#define NN   (HH*WW2)     // 16384
#define CC   256
#define NH   8
#define HID  768
#define EPSF 1e-6f
#define SCALE 0.17677669529663687f   // 32^-0.5

typedef __attribute__((ext_vector_type(8))) short s8v;   // 8 bf16 (4 VGPRs) MFMA A/B frag
typedef __attribute__((ext_vector_type(4))) float f4v;   // MFMA C/D frag

// ---- bf16 helpers (raw ushort storage) ----
__device__ __forceinline__ float bf2f(ushort h) {
    union { unsigned u; float f; } x; x.u = ((unsigned)h) << 16; return x.f;
}
__device__ __forceinline__ ushort f2bf(float f) {
    union { float f; unsigned u; } x; x.f = f;
    unsigned r = (x.u + 0x7FFFu + ((x.u >> 16) & 1u)) >> 16;
    return (ushort)r;
}

typedef __attribute__((address_space(1))) unsigned gu32;
typedef __attribute__((address_space(3))) unsigned lu32;
__device__ __forceinline__ void gl_lds16(const void* g, void* l) {
    __builtin_amdgcn_global_load_lds((gu32*)g, (lu32*)l, 16, 0, 0);
}

// ---------------- LayerNorm -> bf16, 4 rows per block, vectorized ----------------
__global__ __launch_bounds__(256) void ln_bf16v(const float* __restrict__ in,
                                                const float* __restrict__ g,
                                                const float* __restrict__ bta,
                                                ushort* __restrict__ out) {
    int row  = blockIdx.x*4 + (threadIdx.x >> 6);
    int lane = threadIdx.x & 63;
    const float* p = in + (size_t)row*CC + lane*4;
    float4 v = *(const float4*)p;
    float s  = v.x + v.y + v.z + v.w;
    float s2 = v.x*v.x + v.y*v.y + v.z*v.z + v.w*v.w;
    #pragma unroll
    for (int off = 32; off >= 1; off >>= 1) {
        s  += __shfl_xor(s, off);
        s2 += __shfl_xor(s2, off);
    }
    float mean = s * (1.0f/CC);
    float var  = s2 * (1.0f/CC) - mean*mean;
    float r    = rsqrtf(var + EPSF);
    float4 gv = *(const float4*)&g[lane*4];
    float4 bv = *(const float4*)&bta[lane*4];
    ushort4 o;
    o.x = f2bf((v.x-mean)*r*gv.x + bv.x);
    o.y = f2bf((v.y-mean)*r*gv.y + bv.y);
    o.z = f2bf((v.z-mean)*r*gv.z + bv.z);
    o.w = f2bf((v.w-mean)*r*gv.w + bv.w);
    *(ushort4*)&out[(size_t)row*CC + lane*4] = o;
}

// ---------------- weight transpose + bf16 cast: w[K][N] -> wt[N][K] ----------------
__global__ __launch_bounds__(256) void wtrans(const float* __restrict__ w,
                                              ushort* __restrict__ wt, int K, int N) {
    int i = blockIdx.x*256 + threadIdx.x;
    if (i >= K*N) return;
    int k = i / N, n = i - k*N;
    wt[(size_t)n*K + k] = f2bf(w[i]);
}

// ---------------- bf16 MFMA GEMM: C[M,N] = A[M,K] @ Bt[N,K]^T + bias (+resid) ----------------
template<int KDIM, bool OUTBF>
__global__ __launch_bounds__(256) void mfma_gemm(const ushort* __restrict__ A,
                                                 const ushort* __restrict__ Bt,
                                                 const float* __restrict__ bias,
                                                 const float* __restrict__ resid,
                                                 void* __restrict__ Cout,
                                                 int NDIM) {
    __shared__ ushort lsA[128*32];
    __shared__ ushort lsB[128*32];
    int tid  = threadIdx.x;
    int lane = tid & 63;
    int w    = tid >> 6;
    int wm   = w >> 1, wn = w & 1;
    size_t mBase = (size_t)blockIdx.y * 128;
    int    nBase = blockIdx.x * 128;
    int lrow = lane & 15, lq = lane >> 4;

    const ushort* gA = A  + (mBase + w*32 + (lane>>2))*(size_t)KDIM + (lane&3)*8;
    const ushort* gB = Bt + ((size_t)(nBase + w*32 + (lane>>2)))*(size_t)KDIM + (lane&3)*8;
    ushort* lA = lsA + w*1024;
    ushort* lB = lsB + w*1024;

    f4v acc[4][4] = {};

    for (int k0 = 0; k0 < KDIM; k0 += 32) {
        gl_lds16(gA + k0,           lA);
        gl_lds16(gA + k0 + 16*KDIM, lA + 512);
        gl_lds16(gB + k0,           lB);
        gl_lds16(gB + k0 + 16*KDIM, lB + 512);
        __syncthreads();
        s8v af[4], bf[4];
        #pragma unroll
        for (int i = 0; i < 4; ++i)
            af[i] = *(const s8v*)&lsA[(wm*64 + i*16 + lrow)*32 + lq*8];
        #pragma unroll
        for (int j = 0; j < 4; ++j)
            bf[j] = *(const s8v*)&lsB[(wn*64 + j*16 + lrow)*32 + lq*8];
        #pragma unroll
        for (int i = 0; i < 4; ++i)
            #pragma unroll
            for (int j = 0; j < 4; ++j)
                acc[i][j] = __builtin_amdgcn_mfma_f32_16x16x32_bf16(af[i], bf[j], acc[i][j], 0, 0, 0);
        __syncthreads();
    }

    int colBase = nBase + wn*64;
    #pragma unroll
    for (int j = 0; j < 4; ++j) {
        int col = colBase + j*16 + lrow;
        float bs = bias[col];
        #pragma unroll
        for (int i = 0; i < 4; ++i) {
            #pragma unroll
            for (int r = 0; r < 4; ++r) {
                size_t row = mBase + wm*64 + i*16 + lq*4 + r;
                size_t idx = row*(size_t)NDIM + col;
                float v = acc[i][j][r] + bs;
                if constexpr (OUTBF) ((ushort*)Cout)[idx] = f2bf(v);
                else                 ((float*)Cout)[idx] = v + resid[idx];
            }
        }
    }
}

__global__ void zero_kernel(float* __restrict__ p, int nElems) {
    int i = blockIdx.x*256 + threadIdx.x;
    if (i < nElems) p[i] = 0.f;
}

// ------------- kv_raw[bh,kd,vd] += sum_n exp(k)*v ; ksum[bh,kd] += sum_n exp(k) -------------
// (no max-shift: |k| <~ 3 so exp() is safe in fp32; softmax is shift-invariant)
__global__ __launch_bounds__(256) void kv_accum(const ushort* __restrict__ qkv,
                                                float* __restrict__ kv_raw,
                                                float* __restrict__ ksum) {
    int blk = blockIdx.x;
    int chunk = blk & 15;
    int bh = blk >> 4;
    int b = bh >> 3, hh = bh & 7;
    int tid = threadIdx.x;
    __shared__ float ke[32][33];
    __shared__ float vv[32][33];
    int kd = tid >> 3;
    int v0 = (tid & 7) * 4;
    int t  = tid >> 5;
    int cc = tid & 31;
    float acc0=0.f, acc1=0.f, acc2=0.f, acc3=0.f, ks=0.f;
    for (int it = 0; it < 32; ++it) {
        int nb = chunk*1024 + it*32;
        #pragma unroll
        for (int r = 0; r < 4; ++r) {
            int tt = t + r*8;
            size_t rowoff = ((size_t)b*NN + nb + tt)*768;
            ke[tt][cc] = expf(bf2f(qkv[rowoff + 256 + hh*32 + cc]));
            vv[tt][cc] = bf2f(qkv[rowoff + 512 + hh*32 + cc]);
        }
        __syncthreads();
        #pragma unroll
        for (int tt = 0; tt < 32; ++tt) {
            float kval = ke[tt][kd];
            ks   += kval;
            acc0 += kval*vv[tt][v0+0];
            acc1 += kval*vv[tt][v0+1];
            acc2 += kval*vv[tt][v0+2];
            acc3 += kval*vv[tt][v0+3];
        }
        __syncthreads();
    }
    float* dst = kv_raw + ((size_t)bh*32 + kd)*32 + v0;
    atomicAdd(dst+0, acc0); atomicAdd(dst+1, acc1);
    atomicAdd(dst+2, acc2); atomicAdd(dst+3, acc3);
    if (v0 == 0) atomicAdd(&ksum[bh*32 + kd], ks);
}

// ------------- att = scale*(q@(kv/ksum)) + q * dwconv3x3(v), row-sliding -------------
// grid: (xh=2, y=128, b=4), 256 threads = channels. kv column in registers.
__global__ __launch_bounds__(256) void attn_fused(const ushort* __restrict__ qkv,
                                                  const float* __restrict__ kv_raw,
                                                  const float* __restrict__ ksum,
                                                  const float* __restrict__ w,
                                                  const float* __restrict__ wb,
                                                  ushort* __restrict__ att) {
    int xh = blockIdx.x, y = blockIdx.y, b = blockIdx.z;
    int c = threadIdx.x;
    int hd = c >> 5;

    // kvreg[kd] = kv_raw[b,hd,kd,vd] / ksum[b,hd,kd]
    float kvreg[32];
    const float* kvp = kv_raw + (((size_t)(b*NH + hd))*32)*32 + (c & 31);
    const float* ksp = ksum + (b*NH + hd)*32;
    #pragma unroll
    for (int kd = 0; kd < 32; ++kd) kvreg[kd] = kvp[kd*32] / ksp[kd];

    const float* wc = w + c*9;
    float w00=wc[0], w01=wc[1], w02=wc[2],
          w10=wc[3], w11=wc[4], w12=wc[5],
          w20=wc[6], w21=wc[7], w22=wc[8];
    float bw = wb[c];

    const ushort* vbase = qkv + (size_t)b*NN*768 + 512 + c;
    auto ldv = [&](int yy, int xx) -> float {
        if ((unsigned)yy >= (unsigned)HH || (unsigned)xx >= (unsigned)WW2) return 0.f;
        return bf2f(vbase[((size_t)yy*WW2 + xx)*768]);
    };

    int x0 = xh*64;
    float p0 = ldv(y-1, x0-1), p1 = ldv(y, x0-1), p2 = ldv(y+1, x0-1);
    float c0 = ldv(y-1, x0  ), c1 = ldv(y, x0  ), c2 = ldv(y+1, x0  );

    for (int i = 0; i < 64; ++i) {
        int x = x0 + i;
        float n0 = ldv(y-1, x+1), n1 = ldv(y, x+1), n2 = ldv(y+1, x+1);
        float conv = bw + w00*p0 + w01*c0 + w02*n0
                        + w10*p1 + w11*c1 + w12*n1
                        + w20*p2 + w21*c2 + w22*n2;
        size_t bn = (size_t)b*NN + (size_t)y*WW2 + x;
        float qc = bf2f(qkv[bn*768 + c]);
        float f = 0.f;
        #pragma unroll
        for (int kd = 0; kd < 32; ++kd)
            f += __shfl(qc, kd, 32) * kvreg[kd];
        att[bn*CC + c] = f2bf(SCALE*f + qc*conv);
        p0 = c0; p1 = c1; p2 = c2;
        c0 = n0; c1 = n1; c2 = n2;
    }
}

// ------------- MLP dwconv3x3 + skip + exact GELU, row-sliding, 2-batch pair -------------
// grid: (x = xh*3+?? -> dim3(6,128,2)): blockIdx.x = xh + 2*cg; 256 threads = channel chunk.
__global__ __launch_bounds__(256) void dconv_gelu_row(const ushort* __restrict__ hdn,
                                                      const float* __restrict__ w,
                                                      const float* __restrict__ bias,
                                                      ushort* __restrict__ out) {
    int xh = blockIdx.x & 1, cg = blockIdx.x >> 1;  // xh 0..1, cg 0..2
    int y = blockIdx.y, bz = blockIdx.z;            // bz: batch within pair
    int c = cg*256 + threadIdx.x;                   // 0..767

    const float* wc = w + c*9;
    float w00=wc[0], w01=wc[1], w02=wc[2],
          w10=wc[3], w11=wc[4], w12=wc[5],
          w20=wc[6], w21=wc[7], w22=wc[8];
    float bw = bias[c];

    const ushort* base = hdn + (size_t)bz*NN*HID + c;
    auto ldh = [&](int yy, int xx) -> float {
        if ((unsigned)yy >= (unsigned)HH || (unsigned)xx >= (unsigned)WW2) return 0.f;
        return bf2f(base[((size_t)yy*WW2 + xx)*HID]);
    };

    int x0 = xh*64;
    float p0 = ldh(y-1, x0-1), p1 = ldh(y, x0-1), p2 = ldh(y+1, x0-1);
    float c0 = ldh(y-1, x0  ), c1 = ldh(y, x0  ), c2 = ldh(y+1, x0  );

    for (int i = 0; i < 64; ++i) {
        int x = x0 + i;
        float n0 = ldh(y-1, x+1), n1 = ldh(y, x+1), n2 = ldh(y+1, x+1);
        float conv = bw + w00*p0 + w01*c0 + w02*n0
                        + w10*p1 + w11*c1 + w12*n1
                        + w20*p2 + w21*c2 + w22*n2;
        float v = c1 + conv;   // c1 is hdn[y][x][c] (the skip term)
        size_t n = (size_t)bz*NN + (size_t)y*WW2 + x;
        out[n*HID + c] = f2bf(0.5f*v*(1.f + erff(v*0.70710678118654752f)));
        p0 = c0; p1 = c1; p2 = c2;
        c0 = n0; c1 = n1; c2 = n2;
    }
}

extern "C" void kernel_launch(void* const* d_in, const int* in_sizes, int n_in,
                              void* d_out, int out_size, void* d_ws, size_t ws_size,
                              hipStream_t stream) {
    const float* x      = (const float*)d_in[0];
    const float* ln1_g  = (const float*)d_in[3];
    const float* ln1_b  = (const float*)d_in[4];
    const float* qkv_w  = (const float*)d_in[5];
    const float* qkv_b  = (const float*)d_in[6];
    const float* crpe_w = (const float*)d_in[7];
    const float* crpe_b = (const float*)d_in[8];
    const float* proj_w = (const float*)d_in[9];
    const float* proj_b = (const float*)d_in[10];
    const float* ln2_g  = (const float*)d_in[11];
    const float* ln2_b  = (const float*)d_in[12];
    const float* fc1_w  = (const float*)d_in[13];
    const float* fc1_b  = (const float*)d_in[14];
    const float* dconv_w= (const float*)d_in[15];
    const float* dconv_b= (const float*)d_in[16];
    const float* fc2_w  = (const float*)d_in[17];
    const float* fc2_b  = (const float*)d_in[18];
    float* outF = (float*)d_out;
    ushort* ws16 = (ushort*)d_ws;

    // Workspace arena (ushort units) — ~162 MB
    ushort* qkvH  = ws16;                    // 50,331,648  (qkv; later hdn)
    ushort* hdn2  = qkvH + 50331648;         // pair buffer: 25,165,824 used (overlaps sbuf; disjoint lifetime)
    ushort* sbuf  = hdn2 + 12582912;         // 16,777,216  (lnout1 / att / lnout2)
    ushort* wqkvT = sbuf + 16777216;         // 196,608
    ushort* wprojT= wqkvT + 196608;          // 65,536
    ushort* wfc1T = wprojT + 65536;          // 196,608
    ushort* wfc2T = wfc1T + 196608;          // 196,608
    float*  kvraw = (float*)(wfc2T + 196608);// 32,768 f32
    float*  ksumB = kvraw + 32768;           // 1,024 f32

    const int ROWS = BB*NN;   // 65536

    // ---- weight prep ----
    wtrans<<<768, 256, 0, stream>>>(qkv_w,  wqkvT, CC,  3*CC);
    wtrans<<<256, 256, 0, stream>>>(proj_w, wprojT, CC,  CC);
    wtrans<<<768, 256, 0, stream>>>(fc1_w,  wfc1T, CC,  HID);
    wtrans<<<768, 256, 0, stream>>>(fc2_w,  wfc2T, HID, CC);

    // ---- attention branch ----
    ln_bf16v<<<ROWS/4, 256, 0, stream>>>(x, ln1_g, ln1_b, sbuf);
    mfma_gemm<256, true><<<dim3(6, 512), 256, 0, stream>>>(sbuf, wqkvT, qkv_b, nullptr, qkvH, 768);
    zero_kernel<<<132, 256, 0, stream>>>(kvraw, 32768 + 1024);
    kv_accum<<<BB*NH*16, 256, 0, stream>>>(qkvH, kvraw, ksumB);
    attn_fused<<<dim3(2, 128, 4), 256, 0, stream>>>(qkvH, kvraw, ksumB, crpe_w, crpe_b, sbuf);
    // x2 = x + att @ proj_w  -> d_out (fp32)
    mfma_gemm<256, false><<<dim3(2, 512), 256, 0, stream>>>(sbuf, wprojT, proj_b, x, outF, 256);

    // ---- conv-MLP branch ----
    ln_bf16v<<<ROWS/4, 256, 0, stream>>>(outF, ln2_g, ln2_b, sbuf);
    mfma_gemm<256, true><<<dim3(6, 512), 256, 0, stream>>>(sbuf, wfc1T, fc1_b, nullptr, qkvH, 768);
    for (int p = 0; p < 2; ++p) {
        const ushort* hdn_p = qkvH + (size_t)p*2*NN*HID;
        float* xo = outF + (size_t)p*2*NN*CC;
        dconv_gelu_row<<<dim3(6, 128, 2), 256, 0, stream>>>(hdn_p, dconv_w, dconv_b, hdn2);
        // out = x2 + hdn2 @ fc2_w, in-place on d_out
        mfma_gemm<768, false><<<dim3(2, 256), 256, 0, stream>>>(hdn2, wfc2T, fc2_b, xo, xo, 256);
    }
}

// Round 5
// 683.480 us; speedup vs baseline: 3.2605x; 1.0567x over previous
//
#include <hip/hip_runtime.h>
#include <math.h>

// Problem constants (setup_inputs is fixed)
#define BB   4
#define HH   128
#define WW2  128
#define NN   (HH*WW2)     // 16384
#define CC   256
#define NH   8
#define HID  768
#define EPSF 1e-6f
#define SCALE 0.17677669529663687f   // 32^-0.5

typedef __attribute__((ext_vector_type(8))) short s8v;   // 8 bf16 (4 VGPRs) MFMA A/B frag
typedef __attribute__((ext_vector_type(4))) float f4v;   // MFMA C/D frag

// ---- bf16 helpers (raw ushort storage) ----
__device__ __forceinline__ float bf2f(ushort h) {
    union { unsigned u; float f; } x; x.u = ((unsigned)h) << 16; return x.f;
}
__device__ __forceinline__ ushort f2bf(float f) {
    union { float f; unsigned u; } x; x.f = f;
    unsigned r = (x.u + 0x7FFFu + ((x.u >> 16) & 1u)) >> 16;
    return (ushort)r;
}

typedef __attribute__((address_space(1))) unsigned gu32;
typedef __attribute__((address_space(3))) unsigned lu32;
__device__ __forceinline__ void gl_lds16(const void* g, void* l) {
    __builtin_amdgcn_global_load_lds((gu32*)g, (lu32*)l, 16, 0, 0);
}

// ---------------- LayerNorm -> bf16, 4 rows per block, vectorized ----------------
__global__ __launch_bounds__(256) void ln_bf16v(const float* __restrict__ in,
                                                const float* __restrict__ g,
                                                const float* __restrict__ bta,
                                                ushort* __restrict__ out) {
    int row  = blockIdx.x*4 + (threadIdx.x >> 6);
    int lane = threadIdx.x & 63;
    const float* p = in + (size_t)row*CC + lane*4;
    float4 v = *(const float4*)p;
    float s  = v.x + v.y + v.z + v.w;
    float s2 = v.x*v.x + v.y*v.y + v.z*v.z + v.w*v.w;
    #pragma unroll
    for (int off = 32; off >= 1; off >>= 1) {
        s  += __shfl_xor(s, off);
        s2 += __shfl_xor(s2, off);
    }
    float mean = s * (1.0f/CC);
    float var  = s2 * (1.0f/CC) - mean*mean;
    float r    = rsqrtf(var + EPSF);
    float4 gv = *(const float4*)&g[lane*4];
    float4 bv = *(const float4*)&bta[lane*4];
    ushort4 o;
    o.x = f2bf((v.x-mean)*r*gv.x + bv.x);
    o.y = f2bf((v.y-mean)*r*gv.y + bv.y);
    o.z = f2bf((v.z-mean)*r*gv.z + bv.z);
    o.w = f2bf((v.w-mean)*r*gv.w + bv.w);
    *(ushort4*)&out[(size_t)row*CC + lane*4] = o;
}

// ---------------- LDS-tiled weight transpose + bf16 cast: w[K][N] -> wt[N][K] ----------------
__global__ __launch_bounds__(256) void wtrans(const float* __restrict__ w,
                                              ushort* __restrict__ wt, int K, int N) {
    __shared__ float tile[32][33];
    int k0 = blockIdx.x*32, n0 = blockIdx.y*32;
    int c = threadIdx.x & 31, r8 = threadIdx.x >> 5;
    #pragma unroll
    for (int r = 0; r < 4; ++r) {
        int kk = r8 + r*8;
        tile[kk][c] = w[(size_t)(k0+kk)*N + n0 + c];
    }
    __syncthreads();
    #pragma unroll
    for (int r = 0; r < 4; ++r) {
        int nn = r8 + r*8;
        wt[(size_t)(n0+nn)*K + k0 + c] = f2bf(tile[c][nn]);
    }
}

// ---------------- bf16 MFMA GEMM: C[M,N] = A[M,K] @ Bt[N,K]^T + bias (+resid) ----------------
template<int KDIM, bool OUTBF>
__global__ __launch_bounds__(256) void mfma_gemm(const ushort* __restrict__ A,
                                                 const ushort* __restrict__ Bt,
                                                 const float* __restrict__ bias,
                                                 const float* __restrict__ resid,
                                                 void* __restrict__ Cout,
                                                 int NDIM) {
    __shared__ ushort lsA[128*32];
    __shared__ ushort lsB[128*32];
    int tid  = threadIdx.x;
    int lane = tid & 63;
    int w    = tid >> 6;
    int wm   = w >> 1, wn = w & 1;
    size_t mBase = (size_t)blockIdx.y * 128;
    int    nBase = blockIdx.x * 128;
    int lrow = lane & 15, lq = lane >> 4;

    const ushort* gA = A  + (mBase + w*32 + (lane>>2))*(size_t)KDIM + (lane&3)*8;
    const ushort* gB = Bt + ((size_t)(nBase + w*32 + (lane>>2)))*(size_t)KDIM + (lane&3)*8;
    ushort* lA = lsA + w*1024;
    ushort* lB = lsB + w*1024;

    f4v acc[4][4] = {};

    for (int k0 = 0; k0 < KDIM; k0 += 32) {
        gl_lds16(gA + k0,           lA);
        gl_lds16(gA + k0 + 16*KDIM, lA + 512);
        gl_lds16(gB + k0,           lB);
        gl_lds16(gB + k0 + 16*KDIM, lB + 512);
        __syncthreads();
        s8v af[4], bf[4];
        #pragma unroll
        for (int i = 0; i < 4; ++i)
            af[i] = *(const s8v*)&lsA[(wm*64 + i*16 + lrow)*32 + lq*8];
        #pragma unroll
        for (int j = 0; j < 4; ++j)
            bf[j] = *(const s8v*)&lsB[(wn*64 + j*16 + lrow)*32 + lq*8];
        #pragma unroll
        for (int i = 0; i < 4; ++i)
            #pragma unroll
            for (int j = 0; j < 4; ++j)
                acc[i][j] = __builtin_amdgcn_mfma_f32_16x16x32_bf16(af[i], bf[j], acc[i][j], 0, 0, 0);
        __syncthreads();
    }

    int colBase = nBase + wn*64;
    #pragma unroll
    for (int j = 0; j < 4; ++j) {
        int col = colBase + j*16 + lrow;
        float bs = bias[col];
        #pragma unroll
        for (int i = 0; i < 4; ++i) {
            #pragma unroll
            for (int r = 0; r < 4; ++r) {
                size_t row = mBase + wm*64 + i*16 + lq*4 + r;
                size_t idx = row*(size_t)NDIM + col;
                float v = acc[i][j][r] + bs;
                if constexpr (OUTBF) ((ushort*)Cout)[idx] = f2bf(v);
                else                 ((float*)Cout)[idx] = v + resid[idx];
            }
        }
    }
}

// ---- attention proj GEMM with folded q@kv: A=[q | g], B=[WbT_b ; projT], K=512 ----
__global__ __launch_bounds__(256) void mfma_gemm_attn(const ushort* __restrict__ qkv,
                                                      const ushort* __restrict__ gbuf,
                                                      const ushort* __restrict__ WbT,
                                                      const ushort* __restrict__ projT,
                                                      const float* __restrict__ bias,
                                                      const float* __restrict__ resid,
                                                      float* __restrict__ Cout) {
    __shared__ ushort lsA[128*32];
    __shared__ ushort lsB[128*32];
    int tid  = threadIdx.x;
    int lane = tid & 63;
    int w    = tid >> 6;
    int wm   = w >> 1, wn = w & 1;
    int b = blockIdx.z;
    size_t mBase = (size_t)b*NN + (size_t)blockIdx.y * 128;
    int    nBase = blockIdx.x * 128;
    int lrow = lane & 15, lq = lane >> 4;
    int r    = w*32 + (lane>>2);      // staging row within tile
    int koff = (lane&3)*8;

    const ushort* qRow  = qkv  + (mBase + r)*768 + koff;          // q at cols 0..255
    const ushort* gRow  = gbuf + (mBase + r)*256 + koff;
    const ushort* wbRow = WbT  + ((size_t)b*256 + nBase + r)*256 + koff;
    const ushort* pjRow = projT + (size_t)(nBase + r)*256 + koff;
    ushort* lA = lsA + w*1024;
    ushort* lB = lsB + w*1024;

    f4v acc[4][4] = {};

    for (int k0 = 0; k0 < 512; k0 += 32) {
        if (k0 < 256) {
            gl_lds16(qRow + k0,           lA);
            gl_lds16(qRow + k0 + 16*768,  lA + 512);
            gl_lds16(wbRow + k0,          lB);
            gl_lds16(wbRow + k0 + 16*256, lB + 512);
        } else {
            int kk = k0 - 256;
            gl_lds16(gRow + kk,           lA);
            gl_lds16(gRow + kk + 16*256,  lA + 512);
            gl_lds16(pjRow + kk,          lB);
            gl_lds16(pjRow + kk + 16*256, lB + 512);
        }
        __syncthreads();
        s8v af[4], bf[4];
        #pragma unroll
        for (int i = 0; i < 4; ++i)
            af[i] = *(const s8v*)&lsA[(wm*64 + i*16 + lrow)*32 + lq*8];
        #pragma unroll
        for (int j = 0; j < 4; ++j)
            bf[j] = *(const s8v*)&lsB[(wn*64 + j*16 + lrow)*32 + lq*8];
        #pragma unroll
        for (int i = 0; i < 4; ++i)
            #pragma unroll
            for (int j = 0; j < 4; ++j)
                acc[i][j] = __builtin_amdgcn_mfma_f32_16x16x32_bf16(af[i], bf[j], acc[i][j], 0, 0, 0);
        __syncthreads();
    }

    int colBase = nBase + wn*64;
    #pragma unroll
    for (int j = 0; j < 4; ++j) {
        int col = colBase + j*16 + lrow;
        float bs = bias[col];
        #pragma unroll
        for (int i = 0; i < 4; ++i) {
            #pragma unroll
            for (int rr = 0; rr < 4; ++rr) {
                size_t row = mBase + wm*64 + i*16 + lq*4 + rr;
                size_t idx = row*(size_t)CC + col;
                Cout[idx] = acc[i][j][rr] + bs + resid[idx];
            }
        }
    }
}

__global__ void zero_kernel(float* __restrict__ p, int nElems) {
    int i = blockIdx.x*256 + threadIdx.x;
    if (i < nElems) p[i] = 0.f;
}

// ------------- kv_raw[bh,kd,vd] += sum_n exp(k)*v ; ksum[bh,kd] += sum_n exp(k) -------------
// (no max-shift: |k| <~ 3 so exp() is safe in fp32; softmax is shift-invariant)
__global__ __launch_bounds__(256) void kv_accum(const ushort* __restrict__ qkv,
                                                float* __restrict__ kv_raw,
                                                float* __restrict__ ksum) {
    int blk = blockIdx.x;
    int chunk = blk & 15;
    int bh = blk >> 4;
    int b = bh >> 3, hh = bh & 7;
    int tid = threadIdx.x;
    __shared__ float ke[32][36];
    __shared__ float vv[32][36];
    int tok = tid >> 3;           // 0..31 staging token
    int c4  = (tid & 7) * 4;      // 0,4..28 staging channels
    int kd  = tid >> 3;           // compute: fixed k-channel
    int v0  = (tid & 7) * 4;      // compute: 4 v-channels
    float acc0=0.f, acc1=0.f, acc2=0.f, acc3=0.f, ks=0.f;
    for (int it = 0; it < 32; ++it) {
        int nb = chunk*1024 + it*32;
        size_t rowoff = ((size_t)b*NN + nb + tok)*768;
        ushort4 k4 = *(const ushort4*)&qkv[rowoff + 256 + hh*32 + c4];
        ushort4 v4 = *(const ushort4*)&qkv[rowoff + 512 + hh*32 + c4];
        float4 kf, vf;
        kf.x = expf(bf2f(k4.x)); kf.y = expf(bf2f(k4.y));
        kf.z = expf(bf2f(k4.z)); kf.w = expf(bf2f(k4.w));
        vf.x = bf2f(v4.x); vf.y = bf2f(v4.y); vf.z = bf2f(v4.z); vf.w = bf2f(v4.w);
        *(float4*)&ke[tok][c4] = kf;
        *(float4*)&vv[tok][c4] = vf;
        __syncthreads();
        #pragma unroll
        for (int tt = 0; tt < 32; ++tt) {
            float kval = ke[tt][kd];
            float4 vr = *(const float4*)&vv[tt][v0];
            ks   += kval;
            acc0 += kval*vr.x;
            acc1 += kval*vr.y;
            acc2 += kval*vr.z;
            acc3 += kval*vr.w;
        }
        __syncthreads();
    }
    float* dst = kv_raw + ((size_t)bh*32 + kd)*32 + v0;
    atomicAdd(dst+0, acc0); atomicAdd(dst+1, acc1);
    atomicAdd(dst+2, acc2); atomicAdd(dst+3, acc3);
    if (v0 == 0) atomicAdd(&ksum[bh*32 + kd], ks);
}

// ------------- fold: WbT[b][j][h*32+kd] = SCALE * sum_vd (kv/ksum)[b,h,kd,vd] * proj_w[h*32+vd][j] -------------
__global__ __launch_bounds__(256) void kv_fold(const float* __restrict__ kv_raw,
                                               const float* __restrict__ ksum,
                                               const float* __restrict__ proj_w,
                                               ushort* __restrict__ WbT) {
    int bh = blockIdx.x;           // 0..31
    int b = bh >> 3, hh = bh & 7;
    int tid = threadIdx.x;         // j = tid
    __shared__ float kvn[32][33];
    __shared__ float pw[32][256];
    {
        int kd = tid >> 3, v4 = (tid & 7) * 4;
        float inv = 1.0f / ksum[bh*32 + kd];
        const float* src = kv_raw + ((size_t)bh*32 + kd)*32 + v4;
        kvn[kd][v4+0] = src[0]*inv; kvn[kd][v4+1] = src[1]*inv;
        kvn[kd][v4+2] = src[2]*inv; kvn[kd][v4+3] = src[3]*inv;
    }
    for (int vd = 0; vd < 32; ++vd)
        pw[vd][tid] = proj_w[(size_t)(hh*32 + vd)*CC + tid];
    __syncthreads();
    ushort* dst = WbT + ((size_t)b*256 + tid)*256 + hh*32;
    for (int kd = 0; kd < 32; ++kd) {
        float acc = 0.f;
        #pragma unroll
        for (int vd = 0; vd < 32; ++vd) acc += kvn[kd][vd] * pw[vd][tid];
        dst[kd] = f2bf(SCALE * acc);
    }
}

// ------------- g = q * (dwconv3x3(v)+bias), row-sliding, 32 cols/block -------------
// grid: (xq=4, y=128, b=4), 256 threads = channels.
__global__ __launch_bounds__(256) void attn_gate(const ushort* __restrict__ qkv,
                                                 const float* __restrict__ w,
                                                 const float* __restrict__ wb,
                                                 ushort* __restrict__ gbuf) {
    int xq = blockIdx.x, y = blockIdx.y, b = blockIdx.z;
    int c = threadIdx.x;

    const float* wc = w + c*9;
    float w00=wc[0], w01=wc[1], w02=wc[2],
          w10=wc[3], w11=wc[4], w12=wc[5],
          w20=wc[6], w21=wc[7], w22=wc[8];
    float bw = wb[c];

    const ushort* vbase = qkv + (size_t)b*NN*768 + 512 + c;
    auto ldv = [&](int yy, int xx) -> float {
        if ((unsigned)yy >= (unsigned)HH || (unsigned)xx >= (unsigned)WW2) return 0.f;
        return bf2f(vbase[((size_t)yy*WW2 + xx)*768]);
    };

    int x0 = xq*32;
    float p0 = ldv(y-1, x0-1), p1 = ldv(y, x0-1), p2 = ldv(y+1, x0-1);
    float c0 = ldv(y-1, x0  ), c1 = ldv(y, x0  ), c2 = ldv(y+1, x0  );

    for (int i = 0; i < 32; ++i) {
        int x = x0 + i;
        float n0 = ldv(y-1, x+1), n1 = ldv(y, x+1), n2 = ldv(y+1, x+1);
        float conv = bw + w00*p0 + w01*c0 + w02*n0
                        + w10*p1 + w11*c1 + w12*n1
                        + w20*p2 + w21*c2 + w22*n2;
        size_t bn = (size_t)b*NN + (size_t)y*WW2 + x;
        float qc = bf2f(qkv[bn*768 + c]);
        gbuf[bn*CC + c] = f2bf(qc*conv);
        p0 = c0; p1 = c1; p2 = c2;
        c0 = n0; c1 = n1; c2 = n2;
    }
}

// ------------- MLP dwconv3x3 + skip + exact GELU, row-sliding, 2-batch pair -------------
// grid: dim3(12,128,2): blockIdx.x = xq(0..3) + 4*cg(0..2); 256 threads = channel chunk.
__global__ __launch_bounds__(256) void dconv_gelu_row(const ushort* __restrict__ hdn,
                                                      const float* __restrict__ w,
                                                      const float* __restrict__ bias,
                                                      ushort* __restrict__ out) {
    int xq = blockIdx.x & 3, cg = blockIdx.x >> 2;
    int y = blockIdx.y, bz = blockIdx.z;
    int c = cg*256 + threadIdx.x;   // 0..767

    const float* wc = w + c*9;
    float w00=wc[0], w01=wc[1], w02=wc[2],
          w10=wc[3], w11=wc[4], w12=wc[5],
          w20=wc[6], w21=wc[7], w22=wc[8];
    float bw = bias[c];

    const ushort* base = hdn + (size_t)bz*NN*HID + c;
    auto ldh = [&](int yy, int xx) -> float {
        if ((unsigned)yy >= (unsigned)HH || (unsigned)xx >= (unsigned)WW2) return 0.f;
        return bf2f(base[((size_t)yy*WW2 + xx)*HID]);
    };

    int x0 = xq*32;
    float p0 = ldh(y-1, x0-1), p1 = ldh(y, x0-1), p2 = ldh(y+1, x0-1);
    float c0 = ldh(y-1, x0  ), c1 = ldh(y, x0  ), c2 = ldh(y+1, x0  );

    for (int i = 0; i < 32; ++i) {
        int x = x0 + i;
        float n0 = ldh(y-1, x+1), n1 = ldh(y, x+1), n2 = ldh(y+1, x+1);
        float conv = bw + w00*p0 + w01*c0 + w02*n0
                        + w10*p1 + w11*c1 + w12*n1
                        + w20*p2 + w21*c2 + w22*n2;
        float v = c1 + conv;   // c1 is hdn[y][x][c] (the skip term)
        size_t n = (size_t)bz*NN + (size_t)y*WW2 + x;
        out[n*HID + c] = f2bf(0.5f*v*(1.f + erff(v*0.70710678118654752f)));
        p0 = c0; p1 = c1; p2 = c2;
        c0 = n0; c1 = n1; c2 = n2;
    }
}

extern "C" void kernel_launch(void* const* d_in, const int* in_sizes, int n_in,
                              void* d_out, int out_size, void* d_ws, size_t ws_size,
                              hipStream_t stream) {
    const float* x      = (const float*)d_in[0];
    const float* ln1_g  = (const float*)d_in[3];
    const float* ln1_b  = (const float*)d_in[4];
    const float* qkv_w  = (const float*)d_in[5];
    const float* qkv_b  = (const float*)d_in[6];
    const float* crpe_w = (const float*)d_in[7];
    const float* crpe_b = (const float*)d_in[8];
    const float* proj_w = (const float*)d_in[9];
    const float* proj_b = (const float*)d_in[10];
    const float* ln2_g  = (const float*)d_in[11];
    const float* ln2_b  = (const float*)d_in[12];
    const float* fc1_w  = (const float*)d_in[13];
    const float* fc1_b  = (const float*)d_in[14];
    const float* dconv_w= (const float*)d_in[15];
    const float* dconv_b= (const float*)d_in[16];
    const float* fc2_w  = (const float*)d_in[17];
    const float* fc2_b  = (const float*)d_in[18];
    float* outF = (float*)d_out;
    ushort* ws16 = (ushort*)d_ws;

    // Workspace arena (ushort units) — ~162 MB
    ushort* qkvH  = ws16;                    // 50,331,648  (qkv; later hdn)
    ushort* hdn2  = qkvH + 50331648;         // pair buffer: 25,165,824 used (overlaps sbuf; disjoint lifetime)
    ushort* sbuf  = hdn2 + 12582912;         // 16,777,216  (lnout1 / gbuf / lnout2)
    ushort* wqkvT = sbuf + 16777216;         // 196,608
    ushort* wprojT= wqkvT + 196608;          // 65,536
    ushort* wfc1T = wprojT + 65536;          // 196,608
    ushort* wfc2T = wfc1T + 196608;          // 196,608
    ushort* WbT   = wfc2T + 196608;          // 262,144 (per-batch folded kv@proj, bf16)
    float*  kvraw = (float*)(WbT + 262144);  // 32,768 f32
    float*  ksumB = kvraw + 32768;           // 1,024 f32

    const int ROWS = BB*NN;   // 65536

    // ---- weight prep ----
    wtrans<<<dim3(8,24), 256, 0, stream>>>(qkv_w,  wqkvT, CC,  3*CC);
    wtrans<<<dim3(8,8),  256, 0, stream>>>(proj_w, wprojT, CC,  CC);
    wtrans<<<dim3(8,24), 256, 0, stream>>>(fc1_w,  wfc1T, CC,  HID);
    wtrans<<<dim3(24,8), 256, 0, stream>>>(fc2_w,  wfc2T, HID, CC);

    // ---- attention branch ----
    ln_bf16v<<<ROWS/4, 256, 0, stream>>>(x, ln1_g, ln1_b, sbuf);
    mfma_gemm<256, true><<<dim3(6, 512), 256, 0, stream>>>(sbuf, wqkvT, qkv_b, nullptr, qkvH, 768);
    zero_kernel<<<132, 256, 0, stream>>>(kvraw, 32768 + 1024);
    kv_accum<<<BB*NH*16, 256, 0, stream>>>(qkvH, kvraw, ksumB);
    kv_fold<<<32, 256, 0, stream>>>(kvraw, ksumB, proj_w, WbT);
    attn_gate<<<dim3(4, 128, 4), 256, 0, stream>>>(qkvH, crpe_w, crpe_b, sbuf);
    // x2 = x + q@Wb + g@proj_w + proj_b  -> d_out (fp32)
    mfma_gemm_attn<<<dim3(2, 128, 4), 256, 0, stream>>>(qkvH, sbuf, WbT, wprojT,
                                                        proj_b, x, outF);

    // ---- conv-MLP branch ----
    ln_bf16v<<<ROWS/4, 256, 0, stream>>>(outF, ln2_g, ln2_b, sbuf);
    mfma_gemm<256, true><<<dim3(6, 512), 256, 0, stream>>>(sbuf, wfc1T, fc1_b, nullptr, qkvH, 768);
    for (int p = 0; p < 2; ++p) {
        const ushort* hdn_p = qkvH + (size_t)p*2*NN*HID;
        float* xo = outF + (size_t)p*2*NN*CC;
        dconv_gelu_row<<<dim3(12, 128, 2), 256, 0, stream>>>(hdn_p, dconv_w, dconv_b, hdn2);
        // out = x2 + hdn2 @ fc2_w, in-place on d_out
        mfma_gemm<768, false><<<dim3(2, 256), 256, 0, stream>>>(hdn2, wfc2T, fc2_b, xo, xo, 256);
    }
}

// Round 6
// 653.123 us; speedup vs baseline: 3.4120x; 1.0465x over previous
//
#include <hip/hip_runtime.h>
#include <math.h>

// Problem constants (setup_inputs is fixed)
#define BB   4
#define HH   128
#define WW2  128
#define NN   (HH*WW2)     // 16384
#define CC   256
#define NH   8
#define HID  768
#define EPSF 1e-6f
#define SCALE 0.17677669529663687f   // 32^-0.5

typedef __attribute__((ext_vector_type(8))) short s8v;   // 8 bf16 (4 VGPRs) MFMA A/B frag
typedef __attribute__((ext_vector_type(4))) float f4v;   // MFMA C/D frag

// ---- bf16 helpers (raw ushort storage) ----
__device__ __forceinline__ float bf2f(ushort h) {
    union { unsigned u; float f; } x; x.u = ((unsigned)h) << 16; return x.f;
}
__device__ __forceinline__ ushort f2bf(float f) {
    union { float f; unsigned u; } x; x.f = f;
    unsigned r = (x.u + 0x7FFFu + ((x.u >> 16) & 1u)) >> 16;
    return (ushort)r;
}

typedef __attribute__((address_space(1))) unsigned gu32;
typedef __attribute__((address_space(3))) unsigned lu32;
__device__ __forceinline__ void gl_lds16(const void* g, void* l) {
    __builtin_amdgcn_global_load_lds((gu32*)g, (lu32*)l, 16, 0, 0);
}

// ---------------- LayerNorm -> bf16, 4 rows per block, vectorized ----------------
__global__ __launch_bounds__(256) void ln_bf16v(const float* __restrict__ in,
                                                const float* __restrict__ g,
                                                const float* __restrict__ bta,
                                                ushort* __restrict__ out) {
    int row  = blockIdx.x*4 + (threadIdx.x >> 6);
    int lane = threadIdx.x & 63;
    const float* p = in + (size_t)row*CC + lane*4;
    float4 v = *(const float4*)p;
    float s  = v.x + v.y + v.z + v.w;
    float s2 = v.x*v.x + v.y*v.y + v.z*v.z + v.w*v.w;
    #pragma unroll
    for (int off = 32; off >= 1; off >>= 1) {
        s  += __shfl_xor(s, off);
        s2 += __shfl_xor(s2, off);
    }
    float mean = s * (1.0f/CC);
    float var  = s2 * (1.0f/CC) - mean*mean;
    float r    = rsqrtf(var + EPSF);
    float4 gv = *(const float4*)&g[lane*4];
    float4 bv = *(const float4*)&bta[lane*4];
    ushort4 o;
    o.x = f2bf((v.x-mean)*r*gv.x + bv.x);
    o.y = f2bf((v.y-mean)*r*gv.y + bv.y);
    o.z = f2bf((v.z-mean)*r*gv.z + bv.z);
    o.w = f2bf((v.w-mean)*r*gv.w + bv.w);
    *(ushort4*)&out[(size_t)row*CC + lane*4] = o;
}

// ---------------- LDS-tiled weight transpose + bf16 cast: w[K][N] -> wt[N][K] ----------------
__global__ __launch_bounds__(256) void wtrans(const float* __restrict__ w,
                                              ushort* __restrict__ wt, int K, int N) {
    __shared__ float tile[32][33];
    int k0 = blockIdx.x*32, n0 = blockIdx.y*32;
    int c = threadIdx.x & 31, r8 = threadIdx.x >> 5;
    #pragma unroll
    for (int r = 0; r < 4; ++r) {
        int kk = r8 + r*8;
        tile[kk][c] = w[(size_t)(k0+kk)*N + n0 + c];
    }
    __syncthreads();
    #pragma unroll
    for (int r = 0; r < 4; ++r) {
        int nn = r8 + r*8;
        wt[(size_t)(n0+nn)*K + k0 + c] = f2bf(tile[c][nn]);
    }
}

// ---- proj_w[K=256][N=256] -> Bcat[b][n][256+k] (projT half of concatenated B), 4 copies ----
__global__ __launch_bounds__(256) void wtrans_proj(const float* __restrict__ w,
                                                   ushort* __restrict__ Bcat) {
    __shared__ float tile[32][33];
    int k0 = blockIdx.x*32, n0 = blockIdx.y*32;
    int c = threadIdx.x & 31, r8 = threadIdx.x >> 5;
    #pragma unroll
    for (int r = 0; r < 4; ++r) {
        int kk = r8 + r*8;
        tile[kk][c] = w[(size_t)(k0+kk)*CC + n0 + c];
    }
    __syncthreads();
    #pragma unroll
    for (int r = 0; r < 4; ++r) {
        int nn = r8 + r*8;
        ushort val = f2bf(tile[c][nn]);
        #pragma unroll
        for (int b = 0; b < BB; ++b)
            Bcat[((size_t)(b*256 + n0+nn))*512 + 256 + k0 + c] = val;
    }
}

// ---------------- bf16 MFMA GEMM: C[M,N] = A[M,K] @ Bt[N,K]^T + bias (+resid) ----------------
// MODE 0: bf16 out, stride NDIM.  MODE 1: f32 out = acc+bias+resid, stride NDIM.
// MODE 2: qkv split writer: col<256 -> aq (stride 512); col<512 -> kbuf; else vbuf (stride 256).
template<int KDIM, int MODE>
__global__ __launch_bounds__(256) void mfma_gemm(const ushort* __restrict__ A,
                                                 const ushort* __restrict__ Bt,
                                                 const float* __restrict__ bias,
                                                 const float* __restrict__ resid,
                                                 void* __restrict__ Cout,
                                                 ushort* __restrict__ kbuf,
                                                 ushort* __restrict__ vbuf,
                                                 int NDIM) {
    __shared__ ushort lsA[128*32];
    __shared__ ushort lsB[128*32];
    int tid  = threadIdx.x;
    int lane = tid & 63;
    int w    = tid >> 6;
    int wm   = w >> 1, wn = w & 1;
    size_t mBase = (size_t)blockIdx.y * 128;
    int    nBase = blockIdx.x * 128;
    int lrow = lane & 15, lq = lane >> 4;

    const ushort* gA = A  + (mBase + w*32 + (lane>>2))*(size_t)KDIM + (lane&3)*8;
    const ushort* gB = Bt + ((size_t)(nBase + w*32 + (lane>>2)))*(size_t)KDIM + (lane&3)*8;
    ushort* lA = lsA + w*1024;
    ushort* lB = lsB + w*1024;

    f4v acc[4][4] = {};

    for (int k0 = 0; k0 < KDIM; k0 += 32) {
        gl_lds16(gA + k0,           lA);
        gl_lds16(gA + k0 + 16*KDIM, lA + 512);
        gl_lds16(gB + k0,           lB);
        gl_lds16(gB + k0 + 16*KDIM, lB + 512);
        __syncthreads();
        s8v af[4], bf[4];
        #pragma unroll
        for (int i = 0; i < 4; ++i)
            af[i] = *(const s8v*)&lsA[(wm*64 + i*16 + lrow)*32 + lq*8];
        #pragma unroll
        for (int j = 0; j < 4; ++j)
            bf[j] = *(const s8v*)&lsB[(wn*64 + j*16 + lrow)*32 + lq*8];
        #pragma unroll
        for (int i = 0; i < 4; ++i)
            #pragma unroll
            for (int j = 0; j < 4; ++j)
                acc[i][j] = __builtin_amdgcn_mfma_f32_16x16x32_bf16(af[i], bf[j], acc[i][j], 0, 0, 0);
        __syncthreads();
    }

    int colBase = nBase + wn*64;
    #pragma unroll
    for (int j = 0; j < 4; ++j) {
        int col = colBase + j*16 + lrow;
        float bs = bias[col];
        #pragma unroll
        for (int i = 0; i < 4; ++i) {
            #pragma unroll
            for (int r = 0; r < 4; ++r) {
                size_t row = mBase + wm*64 + i*16 + lq*4 + r;
                float v = acc[i][j][r] + bs;
                if constexpr (MODE == 0) {
                    ((ushort*)Cout)[row*(size_t)NDIM + col] = f2bf(v);
                } else if constexpr (MODE == 1) {
                    size_t idx = row*(size_t)NDIM + col;
                    ((float*)Cout)[idx] = v + resid[idx];
                } else {
                    if (col < 256)      ((ushort*)Cout)[row*512 + col] = f2bf(v);
                    else if (col < 512) kbuf[row*256 + col - 256] = f2bf(v);
                    else                vbuf[row*256 + col - 512] = f2bf(v);
                }
            }
        }
    }
}

// ---- attention proj GEMM: A=aq[B*N,512] contiguous, B=Bcat per batch, K=512 ----
__global__ __launch_bounds__(256) void mfma_gemm_attn(const ushort* __restrict__ aq,
                                                      const ushort* __restrict__ Bcat,
                                                      const float* __restrict__ bias,
                                                      const float* __restrict__ resid,
                                                      float* __restrict__ Cout) {
    __shared__ ushort lsA[128*32];
    __shared__ ushort lsB[128*32];
    int tid  = threadIdx.x;
    int lane = tid & 63;
    int w    = tid >> 6;
    int wm   = w >> 1, wn = w & 1;
    int b = blockIdx.z;
    size_t mBase = (size_t)b*NN + (size_t)blockIdx.y * 128;
    int    nBase = blockIdx.x * 128;
    int lrow = lane & 15, lq = lane >> 4;

    const ushort* gA = aq + (mBase + w*32 + (lane>>2))*512 + (lane&3)*8;
    const ushort* gB = Bcat + ((size_t)(b*256 + nBase + w*32 + (lane>>2)))*512 + (lane&3)*8;
    ushort* lA = lsA + w*1024;
    ushort* lB = lsB + w*1024;

    f4v acc[4][4] = {};

    for (int k0 = 0; k0 < 512; k0 += 32) {
        gl_lds16(gA + k0,          lA);
        gl_lds16(gA + k0 + 16*512, lA + 512);
        gl_lds16(gB + k0,          lB);
        gl_lds16(gB + k0 + 16*512, lB + 512);
        __syncthreads();
        s8v af[4], bf[4];
        #pragma unroll
        for (int i = 0; i < 4; ++i)
            af[i] = *(const s8v*)&lsA[(wm*64 + i*16 + lrow)*32 + lq*8];
        #pragma unroll
        for (int j = 0; j < 4; ++j)
            bf[j] = *(const s8v*)&lsB[(wn*64 + j*16 + lrow)*32 + lq*8];
        #pragma unroll
        for (int i = 0; i < 4; ++i)
            #pragma unroll
            for (int j = 0; j < 4; ++j)
                acc[i][j] = __builtin_amdgcn_mfma_f32_16x16x32_bf16(af[i], bf[j], acc[i][j], 0, 0, 0);
        __syncthreads();
    }

    int colBase = nBase + wn*64;
    #pragma unroll
    for (int j = 0; j < 4; ++j) {
        int col = colBase + j*16 + lrow;
        float bs = bias[col];
        #pragma unroll
        for (int i = 0; i < 4; ++i) {
            #pragma unroll
            for (int r = 0; r < 4; ++r) {
                size_t row = mBase + wm*64 + i*16 + lq*4 + r;
                size_t idx = row*(size_t)CC + col;
                Cout[idx] = acc[i][j][r] + bs + resid[idx];
            }
        }
    }
}

__global__ void zero_kernel(float* __restrict__ p, int nElems) {
    int i = blockIdx.x*256 + threadIdx.x;
    if (i < nElems) p[i] = 0.f;
}

// ------------- kv_raw[bh,kd,vd] += sum_n exp(k)*v ; ksum[bh,kd] += sum_n exp(k) -------------
// (no max-shift: |k| <~ 3 so exp() is safe in fp32; softmax is shift-invariant)
__global__ __launch_bounds__(256) void kv_accum(const ushort* __restrict__ kbuf,
                                                const ushort* __restrict__ vbuf,
                                                float* __restrict__ kv_raw,
                                                float* __restrict__ ksum) {
    int blk = blockIdx.x;
    int chunk = blk & 15;
    int bh = blk >> 4;
    int b = bh >> 3, hh = bh & 7;
    int tid = threadIdx.x;
    __shared__ float ke[32][36];
    __shared__ float vv[32][36];
    int tok = tid >> 3;           // 0..31 staging token
    int c4  = (tid & 7) * 4;      // staging channels
    int kd  = tid >> 3;           // compute: fixed k-channel
    int v0  = (tid & 7) * 4;      // compute: 4 v-channels
    float acc0=0.f, acc1=0.f, acc2=0.f, acc3=0.f, ks=0.f;
    for (int it = 0; it < 32; ++it) {
        int nb = chunk*1024 + it*32;
        size_t rowoff = ((size_t)b*NN + nb + tok)*256 + hh*32 + c4;
        ushort4 k4 = *(const ushort4*)&kbuf[rowoff];
        ushort4 v4 = *(const ushort4*)&vbuf[rowoff];
        float4 kf, vf;
        kf.x = expf(bf2f(k4.x)); kf.y = expf(bf2f(k4.y));
        kf.z = expf(bf2f(k4.z)); kf.w = expf(bf2f(k4.w));
        vf.x = bf2f(v4.x); vf.y = bf2f(v4.y); vf.z = bf2f(v4.z); vf.w = bf2f(v4.w);
        *(float4*)&ke[tok][c4] = kf;
        *(float4*)&vv[tok][c4] = vf;
        __syncthreads();
        #pragma unroll
        for (int tt = 0; tt < 32; ++tt) {
            float kval = ke[tt][kd];
            float4 vr = *(const float4*)&vv[tt][v0];
            ks   += kval;
            acc0 += kval*vr.x;
            acc1 += kval*vr.y;
            acc2 += kval*vr.z;
            acc3 += kval*vr.w;
        }
        __syncthreads();
    }
    float* dst = kv_raw + ((size_t)bh*32 + kd)*32 + v0;
    atomicAdd(dst+0, acc0); atomicAdd(dst+1, acc1);
    atomicAdd(dst+2, acc2); atomicAdd(dst+3, acc3);
    if (v0 == 0) atomicAdd(&ksum[bh*32 + kd], ks);
}

// ------------- fold: Bcat[b][j][h*32+kd] = SCALE * sum_vd (kv/ksum)[b,h,kd,vd] * proj_w[h*32+vd][j] -------------
__global__ __launch_bounds__(256) void kv_fold(const float* __restrict__ kv_raw,
                                               const float* __restrict__ ksum,
                                               const float* __restrict__ proj_w,
                                               ushort* __restrict__ Bcat) {
    int bh = blockIdx.x;           // 0..31
    int b = bh >> 3, hh = bh & 7;
    int tid = threadIdx.x;         // j = tid
    __shared__ float kvn[32][33];
    __shared__ float pw[32][256];
    {
        int kd = tid >> 3, v4 = (tid & 7) * 4;
        float inv = 1.0f / ksum[bh*32 + kd];
        const float* src = kv_raw + ((size_t)bh*32 + kd)*32 + v4;
        kvn[kd][v4+0] = src[0]*inv; kvn[kd][v4+1] = src[1]*inv;
        kvn[kd][v4+2] = src[2]*inv; kvn[kd][v4+3] = src[3]*inv;
    }
    for (int vd = 0; vd < 32; ++vd)
        pw[vd][tid] = proj_w[(size_t)(hh*32 + vd)*CC + tid];
    __syncthreads();
    ushort* dst = Bcat + ((size_t)(b*256 + tid))*512 + hh*32;
    for (int kd = 0; kd < 32; ++kd) {
        float acc = 0.f;
        #pragma unroll
        for (int vd = 0; vd < 32; ++vd) acc += kvn[kd][vd] * pw[vd][tid];
        dst[kd] = f2bf(SCALE * acc);
    }
}

// ------------- g = q * (dwconv3x3(v)+bias) -> aq[:,256:512]; 2 rows/block, ring -------------
// grid: (xq=4, yq=64, b=4), 256 threads = channels.
__global__ __launch_bounds__(256) void attn_gate(const ushort* __restrict__ vbuf,
                                                 const float* __restrict__ w,
                                                 const float* __restrict__ wb,
                                                 ushort* __restrict__ aq) {
    int xq = blockIdx.x, yq = blockIdx.y, b = blockIdx.z;
    int c = threadIdx.x;
    int y0 = yq*2;

    const float* wc = w + c*9;
    float w00=wc[0], w01=wc[1], w02=wc[2],
          w10=wc[3], w11=wc[4], w12=wc[5],
          w20=wc[6], w21=wc[7], w22=wc[8];
    float bw = wb[c];

    const ushort* vbase = vbuf + (size_t)b*NN*256 + c;
    auto ldv = [&](int yy, int xx) -> float {
        if ((unsigned)yy >= (unsigned)HH || (unsigned)xx >= (unsigned)WW2) return 0.f;
        return bf2f(vbase[((size_t)yy*WW2 + xx)*256]);
    };

    int x0 = xq*32;
    float rp[4], rc[4];
    #pragma unroll
    for (int r = 0; r < 4; ++r) {
        rp[r] = ldv(y0-1+r, x0-1);
        rc[r] = ldv(y0-1+r, x0);
    }

    #pragma unroll 4
    for (int i = 0; i < 32; ++i) {
        int x = x0 + i;
        float rn[4];
        #pragma unroll
        for (int r = 0; r < 4; ++r) rn[r] = ldv(y0-1+r, x+1);
        #pragma unroll
        for (int o = 0; o < 2; ++o) {
            float conv = bw + w00*rp[o] + w01*rc[o] + w02*rn[o]
                            + w10*rp[o+1] + w11*rc[o+1] + w12*rn[o+1]
                            + w20*rp[o+2] + w21*rc[o+2] + w22*rn[o+2];
            size_t bn = (size_t)b*NN + (size_t)(y0+o)*WW2 + x;
            float qc = bf2f(aq[bn*512 + c]);
            aq[bn*512 + 256 + c] = f2bf(qc*conv);
        }
        #pragma unroll
        for (int r = 0; r < 4; ++r) { rp[r] = rc[r]; rc[r] = rn[r]; }
    }
}

// ------------- MLP dwconv3x3 + skip + exact GELU; 2 ch/thread, 2 rows/block, ring -------------
// grid: dim3(4, 64, 2), 384 threads (ch pairs 0..383 -> channels 2t,2t+1).
__global__ __launch_bounds__(384) void dconv_gelu_row2(const ushort* __restrict__ hdn,
                                                       const float* __restrict__ w,
                                                       const float* __restrict__ bias,
                                                       ushort* __restrict__ out) {
    int xq = blockIdx.x, yq = blockIdx.y, bz = blockIdx.z;
    int c = threadIdx.x * 2;       // channels c, c+1
    int y0 = yq*2;

    float wA[9], wB[9];
    #pragma unroll
    for (int i = 0; i < 9; ++i) { wA[i] = w[c*9 + i]; wB[i] = w[(c+1)*9 + i]; }
    float bw0 = bias[c], bw1 = bias[c+1];

    const ushort* base = hdn + (size_t)bz*NN*HID + c;
    auto ld2 = [&](int yy, int xx) -> float2 {
        if ((unsigned)yy >= (unsigned)HH || (unsigned)xx >= (unsigned)WW2)
            return make_float2(0.f, 0.f);
        ushort2 u = *(const ushort2*)&base[((size_t)yy*WW2 + xx)*HID];
        return make_float2(bf2f(u.x), bf2f(u.y));
    };

    int x0 = xq*32;
    float2 rp[4], rc[4];
    #pragma unroll
    for (int r = 0; r < 4; ++r) {
        rp[r] = ld2(y0-1+r, x0-1);
        rc[r] = ld2(y0-1+r, x0);
    }

    #pragma unroll 4
    for (int i = 0; i < 32; ++i) {
        int x = x0 + i;
        float2 rn[4];
        #pragma unroll
        for (int r = 0; r < 4; ++r) rn[r] = ld2(y0-1+r, x+1);
        #pragma unroll
        for (int o = 0; o < 2; ++o) {
            float conv0 = bw0 + wA[0]*rp[o].x + wA[1]*rc[o].x + wA[2]*rn[o].x
                              + wA[3]*rp[o+1].x + wA[4]*rc[o+1].x + wA[5]*rn[o+1].x
                              + wA[6]*rp[o+2].x + wA[7]*rc[o+2].x + wA[8]*rn[o+2].x;
            float conv1 = bw1 + wB[0]*rp[o].y + wB[1]*rc[o].y + wB[2]*rn[o].y
                              + wB[3]*rp[o+1].y + wB[4]*rc[o+1].y + wB[5]*rn[o+1].y
                              + wB[6]*rp[o+2].y + wB[7]*rc[o+2].y + wB[8]*rn[o+2].y;
            float v0 = rc[o+1].x + conv0;   // center tap = skip
            float v1 = rc[o+1].y + conv1;
            ushort2 res;
            res.x = f2bf(0.5f*v0*(1.f + erff(v0*0.70710678118654752f)));
            res.y = f2bf(0.5f*v1*(1.f + erff(v1*0.70710678118654752f)));
            size_t n = (size_t)bz*NN + (size_t)(y0+o)*WW2 + x;
            *(ushort2*)&out[n*HID + c] = res;
        }
        #pragma unroll
        for (int r = 0; r < 4; ++r) { rp[r] = rc[r]; rc[r] = rn[r]; }
    }
}

extern "C" void kernel_launch(void* const* d_in, const int* in_sizes, int n_in,
                              void* d_out, int out_size, void* d_ws, size_t ws_size,
                              hipStream_t stream) {
    const float* x      = (const float*)d_in[0];
    const float* ln1_g  = (const float*)d_in[3];
    const float* ln1_b  = (const float*)d_in[4];
    const float* qkv_w  = (const float*)d_in[5];
    const float* qkv_b  = (const float*)d_in[6];
    const float* crpe_w = (const float*)d_in[7];
    const float* crpe_b = (const float*)d_in[8];
    const float* proj_w = (const float*)d_in[9];
    const float* proj_b = (const float*)d_in[10];
    const float* ln2_g  = (const float*)d_in[11];
    const float* ln2_b  = (const float*)d_in[12];
    const float* fc1_w  = (const float*)d_in[13];
    const float* fc1_b  = (const float*)d_in[14];
    const float* dconv_w= (const float*)d_in[15];
    const float* dconv_b= (const float*)d_in[16];
    const float* fc2_w  = (const float*)d_in[17];
    const float* fc2_b  = (const float*)d_in[18];
    float* outF = (float*)d_out;
    ushort* ws16 = (ushort*)d_ws;

    // Workspace arena (ushort units) — ~170 MB
    ushort* aq    = ws16;                    // 33,554,432  [B*N,512]: q | gate
    ushort* kbuf  = aq + 33554432;           // 16,777,216
    ushort* vbuf  = kbuf + 16777216;         // 16,777,216
    ushort* sbuf  = vbuf + 16777216;         // 16,777,216  (ln1 out / ln2 out)
    ushort* wqkvT = sbuf + 16777216;         // 196,608
    ushort* wfc1T = wqkvT + 196608;          // 196,608
    ushort* wfc2T = wfc1T + 196608;          // 196,608
    ushort* Bcat  = wfc2T + 196608;          // 524,288  [4][256][512] = WbT | projT
    float*  kvraw = (float*)(Bcat + 524288); // 32,768 f32
    float*  ksumB = kvraw + 32768;           // 1,024 f32
    ushort* hdn   = ws16;                    // alias aq+kbuf: 50,331,648 (after attn done)
    ushort* hdn2  = vbuf;                    // alias vbuf + dead sbuf head: 25,165,824

    const int ROWS = BB*NN;   // 65536

    // ---- weight prep ----
    wtrans<<<dim3(8,24), 256, 0, stream>>>(qkv_w,  wqkvT, CC,  3*CC);
    wtrans<<<dim3(8,24), 256, 0, stream>>>(fc1_w,  wfc1T, CC,  HID);
    wtrans<<<dim3(24,8), 256, 0, stream>>>(fc2_w,  wfc2T, HID, CC);
    wtrans_proj<<<dim3(8,8), 256, 0, stream>>>(proj_w, Bcat);

    // ---- attention branch ----
    ln_bf16v<<<ROWS/4, 256, 0, stream>>>(x, ln1_g, ln1_b, sbuf);
    mfma_gemm<256, 2><<<dim3(6, 512), 256, 0, stream>>>(
        sbuf, wqkvT, qkv_b, nullptr, aq, kbuf, vbuf, 0);
    zero_kernel<<<132, 256, 0, stream>>>(kvraw, 32768 + 1024);
    kv_accum<<<BB*NH*16, 256, 0, stream>>>(kbuf, vbuf, kvraw, ksumB);
    kv_fold<<<32, 256, 0, stream>>>(kvraw, ksumB, proj_w, Bcat);
    attn_gate<<<dim3(4, 64, 4), 256, 0, stream>>>(vbuf, crpe_w, crpe_b, aq);
    // x2 = x + q@Wb + g@proj_w + proj_b  -> d_out (fp32)
    mfma_gemm_attn<<<dim3(2, 128, 4), 256, 0, stream>>>(aq, Bcat, proj_b, x, outF);

    // ---- conv-MLP branch ----
    ln_bf16v<<<ROWS/4, 256, 0, stream>>>(outF, ln2_g, ln2_b, sbuf);
    mfma_gemm<256, 0><<<dim3(6, 512), 256, 0, stream>>>(
        sbuf, wfc1T, fc1_b, nullptr, hdn, nullptr, nullptr, 768);
    for (int p = 0; p < 2; ++p) {
        const ushort* hdn_p = hdn + (size_t)p*2*NN*HID;
        float* xo = outF + (size_t)p*2*NN*CC;
        dconv_gelu_row2<<<dim3(4, 64, 2), 384, 0, stream>>>(hdn_p, dconv_w, dconv_b, hdn2);
        // out = x2 + hdn2 @ fc2_w, in-place on d_out
        mfma_gemm<768, 1><<<dim3(2, 256), 256, 0, stream>>>(
            hdn2, wfc2T, fc2_b, xo, xo, nullptr, nullptr, 256);
    }
}